// Round 12
// baseline (1450.692 us; speedup 1.0000x reference)
//
#include <hip/hip_runtime.h>
#include <math.h>

#define B_SZ 64
#define WID 128
#define NPT 4096
#define MODES 128
#define LSEG 20
#define MCH 8
#define LM 160   // LSEG*MCH

typedef _Float16 half8 __attribute__((ext_vector_type(8)));
typedef float f32x4 __attribute__((ext_vector_type(4)));

#define LO_SCALE 2048.0f
#define LO_INV   (1.0f/2048.0f)

// ---------------- workspace layout (bytes), total ~161.6 MB ----------------
static constexpr size_t BY_F    = 0;                       // fp32 [8192][256]
static constexpr size_t BY_wsum = BY_F + 8388608;          // fp32 [4][4][128][128]
static constexpr size_t BY_Wcre = BY_wsum + 1048576;       // fp32 [160][128]
static constexpr size_t BY_Wcim = BY_Wcre + 81920;
static constexpr size_t BY_wl   = BY_Wcim + 81920;         // fp32 [160] (pad)
static constexpr size_t BY_wr   = BY_wl + 1024;
static constexpr size_t BY_li   = BY_wr + 1024;            // int [160]
static constexpr size_t BY_magp = BY_li + 1024;            // fp32 [64][16][128]
static constexpr size_t BY_gate = BY_magp + 524288;        // fp32 [64][128]
static constexpr size_t BY_hh   = BY_gate + 32768;         // f16 [64][128][4096] split-hi
static constexpr size_t BY_hl   = BY_hh + 67108864;        // f16 split-lo
static constexpr size_t BY_Tfh  = BY_hl + 67108864;        // f16 frag-packed fwd [16][128][64][8]
static constexpr size_t BY_Tfl  = BY_Tfh + 2097152;
static constexpr size_t BY_Tih  = BY_Tfl + 2097152;        // f16 frag-packed inv [256][8][64][8]
static constexpr size_t BY_Til  = BY_Tih + 2097152;
static constexpr size_t BY_Xh   = BY_Til + 2097152;        // f16 frag-packed [64][8][8][64][8]
static constexpr size_t BY_Xl   = BY_Xh + 4194304;
static constexpr size_t BY_cWh  = BY_Xl + 4194304;         // f16 frag-packed [4][8][4][64][8]
static constexpr size_t BY_cWl  = BY_cWh + 131072;
static constexpr size_t BY_f1h  = BY_cWl + 131072;         // f16 [128][128] (linear)
static constexpr size_t BY_f1l  = BY_f1h + 32768;
static constexpr size_t BY_end  = BY_f1l + 32768;

__device__ __forceinline__ float gelu_f(float x){
    return 0.5f*x*(1.0f+erff(x*0.70710678118654752f));
}
__device__ __forceinline__ void split_f16(float v, _Float16& hi, _Float16& lo){
    hi = (_Float16)v;
    lo = (_Float16)((v - (float)hi)*LO_SCALE);
}

// ---------------- tables (split f16, MFMA-fragment-packed) ----------------
__global__ void k_tables(_Float16* __restrict__ Tffh, _Float16* __restrict__ Tffl,
                         _Float16* __restrict__ Tifh, _Float16* __restrict__ Tifl){
    int idx = blockIdx.x*256 + threadIdx.x;   // 4096*256
    int n = idx >> 8, k2 = idx & 255;
    int f = k2 >> 1;
    int m = (n*f) & 4095;
    double th = (double)m * (3.14159265358979323846/2048.0);
    double s, c; sincos(th, &s, &c);
    float vf = (k2&1) ? (float)(-s) : (float)c;
    {
        _Float16 h1,l1; split_f16(vf, h1, l1);
        int ct = k2>>4, ck = n>>5;
        int lane = (((n>>3)&3)<<4) | (k2&15);
        int j = n & 7;
        size_t off = (((size_t)(ct*128 + ck))<<9) + lane*8 + j;
        Tffh[off] = h1; Tffl[off] = l1;
    }
    float vi;
    if (k2 == 0)      vi = 1.0f;
    else if (k2 == 1) vi = 0.0f;
    else              vi = vf;
    {
        _Float16 h2,l2; split_f16(vi, h2, l2);
        int nt = n>>4, ck2 = k2>>5;
        int lane = (((k2>>3)&3)<<4) | (n&15);
        int j = k2 & 7;
        size_t off = (((size_t)(nt*8 + ck2))<<9) + lane*8 + j;
        Tifh[off] = h2; Tifl[off] = l2;
    }
}

__global__ void k_cft_tables(float* __restrict__ Wre, float* __restrict__ Wim,
                             float* __restrict__ wl, float* __restrict__ wr,
                             int* __restrict__ li){
    int idx = blockIdx.x*128 + threadIdx.x;   // 160*128
    if (idx >= LM*MODES) return;
    int lm = idx >> 7;  int f = idx & 127;
    int l = lm / MCH, m = lm % MCH;
    const double PI = 3.14159265358979323846;
    double nodes[8], Tm[8];
    #pragma unroll
    for (int j=0;j<8;j++){
        nodes[j] = -cos((2.0*j+1.0)*PI/16.0);
        Tm[j] = cos((double)m * acos(nodes[j]));
    }
    double wp = (double)f * PI * 0.05;
    double cwre=0.0, cwim=0.0;
    #pragma unroll
    for (int j=0;j<8;j++){
        double sj, cj; sincos(nodes[j]*wp, &sj, &cj);
        cwre += Tm[j]*cj;
        cwim -= Tm[j]*sj;
    }
    cwre *= 0.025; cwim *= 0.025;
    int r = (f*l) % 20;
    double sa = 2.0*PI*(double)r/20.0;
    double shre = cos(sa), shim = -sin(sa);
    Wre[lm*128+f] = (float)(shre*cwre - shim*cwim);
    Wim[lm*128+f] = (float)(shre*cwim + shim*cwre);
    if (f == 0){
        double v = (double)l/20.0 + 0.025*(nodes[m]+1.0);
        int rr = (int)ceil(v*4095.0);
        if (rr > 4095) rr = 4095;
        if (rr < 1) rr = 1;
        int le = rr-1;
        double tl = (double)le/4095.0, tr = (double)rr/4095.0;
        double wrv = (v - tl)/(tr - tl);
        li[lm] = le;
        wl[lm] = (float)(1.0 - wrv);
        wr[lm] = (float)wrv;
    }
}

// sum wA/wB over mode axis
__global__ void k_wsum(const float* __restrict__ wAre, const float* __restrict__ wAim,
                       const float* __restrict__ wBre, const float* __restrict__ wBim,
                       float* __restrict__ out){
    int row  = blockIdx.x*4 + (threadIdx.x>>6);
    int lane = threadIdx.x & 63;
    const float* src = (blockIdx.y==0)?wAre:(blockIdx.y==1)?wAim:(blockIdx.y==2)?wBre:wBim;
    float v = src[(size_t)row*128 + lane] + src[(size_t)row*128 + 64 + lane];
    #pragma unroll
    for (int o=32;o>0;o>>=1) v += __shfl_down(v, o);
    if (lane==0) out[(size_t)blockIdx.y*65536 + row] = v;
}

// pre-split weights; convW in fragment-packed order, fc1W linear
__global__ void k_wsplit(const float* __restrict__ convW, const float* __restrict__ fc1W,
                         _Float16* __restrict__ cWh, _Float16* __restrict__ cWl,
                         _Float16* __restrict__ f1h, _Float16* __restrict__ f1l){
    int idx = blockIdx.x*256 + threadIdx.x;   // 81920
    if (idx < 65536){
        _Float16 hi,lo; split_f16(convW[idx], hi, lo);
        int layer = idx >> 14, o = (idx >> 7) & 127, k = idx & 127;
        int ot = o>>4, ck = k>>5;
        int lane = ((k>>3)&3)*16 + (o&15);
        int j = k & 7;
        size_t off = (((size_t)((layer*8 + ot)*4 + ck))<<9) + (size_t)lane*8 + j;
        cWh[off]=hi; cWl[off]=lo;
    } else {
        int j = idx - 65536;
        _Float16 hi,lo; split_f16(fc1W[j], hi, lo);
        f1h[j]=hi; f1l[j]=lo;
    }
}

// ---------------- lift: write split h ----------------
__global__ void k_h0(const float* __restrict__ x, const float* __restrict__ w0,
                     const float* __restrict__ b0,
                     _Float16* __restrict__ hh, _Float16* __restrict__ hl){
    int idx = blockIdx.x*256 + threadIdx.x;  // 64*128*512
    int n8 = idx & 511;
    int w  = (idx >> 9) & 127;
    int b  = idx >> 16;
    int n0 = n8*8;
    float w00 = w0[w*2], w01 = w0[w*2+1], bb = b0[w];
    const float* xr = &x[((size_t)b<<12) + n0];
    float4 x0 = *reinterpret_cast<const float4*>(xr);
    float4 x1 = *reinterpret_cast<const float4*>(xr+4);
    float xv[8]={x0.x,x0.y,x0.z,x0.w,x1.x,x1.y,x1.z,x1.w};
    half8 vh, vl;
    #pragma unroll
    for (int q=0;q<8;q++){
        float g = (float)(n0+q) * (1.0f/4095.0f);
        float v = xv[q]*w00 + g*w01 + bb;
        _Float16 hi,lo; split_f16(v,hi,lo);
        vh[q]=hi; vl[q]=lo;
    }
    size_t o = ((size_t)(b*128+w))*4096 + n0;
    *reinterpret_cast<half8*>(&hh[o]) = vh;
    *reinterpret_cast<half8*>(&hl[o]) = vl;
}

// ---------------- CFT magnitude (16 groups of 8 channels) ----------------
__global__ void k_cft(const _Float16* __restrict__ hh, const _Float16* __restrict__ hl,
                      const float* __restrict__ Wre, const float* __restrict__ Wim,
                      const float* __restrict__ wl, const float* __restrict__ wr,
                      const int* __restrict__ li, float* __restrict__ magp){
    int b = blockIdx.x, cg = blockIdx.y;
    int f = threadIdx.x;   // 128
    __shared__ float sig[LM];
    __shared__ float swl[LM], swr[LM];
    __shared__ int   sli[LM];
    for (int s=f; s<LM; s+=128){ swl[s]=wl[s]; swr[s]=wr[s]; sli[s]=li[s]; }
    __syncthreads();
    float acc = 0.f;
    for (int cc=0; cc<8; cc++){
        int c = cg*8 + cc;
        const _Float16* rh = hh + ((size_t)(b*128+c))*4096;
        const _Float16* rl = hl + ((size_t)(b*128+c))*4096;
        for (int s=f; s<LM; s+=128){
            int le = sli[s];
            float v0 = (float)rh[le]   + (float)rl[le]*LO_INV;
            float v1 = (float)rh[le+1] + (float)rl[le+1]*LO_INV;
            sig[s] = swl[s]*v0 + swr[s]*v1;
        }
        __syncthreads();
        float re=0.f, im=0.f;
        #pragma unroll 8
        for (int s=0;s<LM;s++){
            float sv = sig[s];
            re = fmaf(sv, Wre[s*128+f], re);
            im = fmaf(sv, Wim[s*128+f], im);
        }
        acc += sqrtf(re*re+im*im);
        __syncthreads();
    }
    magp[(b*16+cg)*128 + f] = acc;
}

__global__ void k_gate(const float* __restrict__ magp, const float* __restrict__ gW,
                       const float* __restrict__ gB, float* __restrict__ gate, int layer){
    int b = blockIdx.x, w = threadIdx.x;
    __shared__ float ms[128];
    float s = 0.f;
    #pragma unroll
    for (int g=0; g<16; g++) s += magp[(b*16+g)*128 + w];
    ms[w] = s * (1.0f/128.0f);
    __syncthreads();
    const float* gwr = gW + ((size_t)layer*128 + w)*128;
    float a = gB[layer*128 + w];
    #pragma unroll 8
    for (int fq=0; fq<128; fq++) a = fmaf(ms[fq], gwr[fq], a);
    gate[b*128+w] = 1.0f/(1.0f+expf(-a));
}

// ---------------- forward DFT: A-only LDS dbuf, B direct from packed fragments ----------------
__global__ __launch_bounds__(256) void k_fdft(
        const _Float16* __restrict__ hh, const _Float16* __restrict__ hl,
        const _Float16* __restrict__ Tffh, const _Float16* __restrict__ Tffl,
        float* __restrict__ F){
    __shared__ _Float16 Ah[2][64][40], Al[2][64][40];
    int id = blockIdx.x;
    int swz = (id & 7)*64 + (id >> 3);        // bijective for 512
    int bx = swz & 3, by = swz >> 2;
    int col0 = bx*64, row0 = by*64;
    int tid = threadIdx.x, lane = tid & 63, w = tid >> 6;
    int wr = (w>>1)*32, wc = (w&1)*32;
    int l15 = lane & 15, l4 = lane >> 4;
    f32x4 acc[2][2] = {}; f32x4 acc2[2][2] = {};
    int srow = tid >> 2, sseg = tid & 3;
    const _Float16* pa_h = hh + (size_t)(row0+srow)*4096 + sseg*8;
    const _Float16* pa_l = hl + (size_t)(row0+srow)*4096 + sseg*8;
    int ct0 = (col0 + wc) >> 4;
    const _Float16* pfh = Tffh + (size_t)lane*8;
    const _Float16* pfl = Tffl + (size_t)lane*8;
    half8 a0h,a0l,a1h,a1l;
    half8 bf0[4], bf1[4];
#define LOADA(xh,xl,ck) do{ \
    xh = *reinterpret_cast<const half8*>(pa_h + (size_t)(ck)*32); \
    xl = *reinterpret_cast<const half8*>(pa_l + (size_t)(ck)*32); }while(0)
#define WRITEA(xh,xl,buf) do{ \
    *reinterpret_cast<half8*>(&Ah[buf][srow][sseg*8]) = xh; \
    *reinterpret_cast<half8*>(&Al[buf][srow][sseg*8]) = xl; }while(0)
#define LOADB(dst,ck) do{ \
    dst[0] = *reinterpret_cast<const half8*>(pfh + (((size_t)(ct0  )*128 + (ck))<<9)); \
    dst[1] = *reinterpret_cast<const half8*>(pfh + (((size_t)(ct0+1)*128 + (ck))<<9)); \
    dst[2] = *reinterpret_cast<const half8*>(pfl + (((size_t)(ct0  )*128 + (ck))<<9)); \
    dst[3] = *reinterpret_cast<const half8*>(pfl + (((size_t)(ct0+1)*128 + (ck))<<9)); }while(0)
#define MMF(buf,BF) do{ \
    _Pragma("unroll") for (int i=0;i<2;i++){ \
        half8 fah = *reinterpret_cast<const half8*>(&Ah[buf][wr + i*16 + l15][l4*8]); \
        half8 fal = *reinterpret_cast<const half8*>(&Al[buf][wr + i*16 + l15][l4*8]); \
        _Pragma("unroll") for (int j=0;j<2;j++){ \
            acc[i][j]  = __builtin_amdgcn_mfma_f32_16x16x32_f16(fah, BF[j],   acc[i][j], 0,0,0); \
            acc2[i][j] = __builtin_amdgcn_mfma_f32_16x16x32_f16(fah, BF[2+j], acc2[i][j],0,0,0); \
            acc2[i][j] = __builtin_amdgcn_mfma_f32_16x16x32_f16(fal, BF[j],   acc2[i][j],0,0,0); } } }while(0)
    LOADA(a0h,a0l,0); WRITEA(a0h,a0l,0);
    LOADA(a0h,a0l,1);
    LOADA(a1h,a1l,2);
    LOADB(bf0,0); LOADB(bf1,1);
    __syncthreads();
    for (int tt=0; tt<64; ++tt){
        int t = tt*2;
        MMF(0,bf0);
        WRITEA(a0h,a0l,1);                  // chunk t+1
        if (t+2 < 128) LOADB(bf0, t+2);
        if (t+3 < 128) LOADA(a0h,a0l, t+3);
        __syncthreads();
        MMF(1,bf1);
        if (t+2 < 128) WRITEA(a1h,a1l,0);   // chunk t+2
        if (t+3 < 128) LOADB(bf1, t+3);
        if (t+4 < 128) LOADA(a1h,a1l, t+4);
        __syncthreads();
    }
#undef LOADA
#undef WRITEA
#undef LOADB
#undef MMF
    #pragma unroll
    for (int i=0;i<2;i++)
        #pragma unroll
        for (int j=0;j<2;j++)
            #pragma unroll
            for (int r=0;r<4;r++){
                int row = row0 + wr + i*16 + l4*4 + r;
                int col = col0 + wc + j*16 + l15;
                F[(size_t)row*256 + col] = acc[i][j][r] + acc2[i][j][r]*LO_INV;
            }
}

// ---------------- mode mix: X = g*(F.wA) + (1-g)*(F.wB), scaled, split, frag-packed ----------------
__global__ __launch_bounds__(256) void k_modemix(const float* __restrict__ F,
        const float* __restrict__ wsum, const float* __restrict__ gate,
        _Float16* __restrict__ Xfh, _Float16* __restrict__ Xfl, int layer){
    int b = blockIdx.x, og = blockIdx.y;
    __shared__ float Fs[16][256];
    __shared__ float Wa_re[128][8], Wa_im[128][8], Wb_re[128][8], Wb_im[128][8];
    int tid = threadIdx.x;
    for (int e=tid; e<1024; e+=256){
        int i = e>>3, oo = e&7;
        size_t base = ((size_t)layer*128 + i)*128 + og*8 + oo;
        Wa_re[i][oo] = wsum[0*65536 + base];
        Wa_im[i][oo] = wsum[1*65536 + base];
        Wb_re[i][oo] = wsum[2*65536 + base];
        Wb_im[i][oo] = wsum[3*65536 + base];
    }
    int f = tid & 127, half = tid >> 7;
    float pre[4]={},pim[4]={},qre[4]={},qim[4]={};
    for (int i0=0;i0<128;i0+=16){
        for (int e=tid; e<4096; e+=256){
            int ii = e >> 8, k2 = e & 255;
            Fs[ii][k2] = F[((size_t)(b*128 + i0+ii))*256 + k2];
        }
        __syncthreads();
        #pragma unroll
        for (int ii=0; ii<16; ii++){
            float fre = Fs[ii][2*f], fim = Fs[ii][2*f+1];
            int i = i0+ii;
            #pragma unroll
            for (int q=0;q<4;q++){
                int oo = half*4+q;
                float are=Wa_re[i][oo], aim=Wa_im[i][oo];
                float bre=Wb_re[i][oo], bim=Wb_im[i][oo];
                pre[q] = fmaf(fre, are, fmaf(-fim, aim, pre[q]));
                pim[q] = fmaf(fre, aim, fmaf( fim, are, pim[q]));
                qre[q] = fmaf(fre, bre, fmaf(-fim, bim, qre[q]));
                qim[q] = fmaf(fre, bim, fmaf( fim, bre, qim[q]));
            }
        }
        __syncthreads();
    }
    #pragma unroll
    for (int q=0;q<4;q++){
        int o = og*8 + half*4 + q;
        float g = gate[b*128+o];
        float xre = g*pre[q] + (1.f-g)*qre[q];
        float xim = g*pim[q] + (1.f-g)*qim[q];
        float s = (f==0) ? (1.0f/4096.0f) : (2.0f/4096.0f);
        xre *= s; xim *= s;
        if (f==0) xim = 0.f;
        int k2a = 2*f;
        int ot = o >> 4, ck = k2a >> 5;
        int lane2 = ((k2a>>3)&3)*16 + (o&15);
        int j = k2a & 7;
        size_t off = (((size_t)((b*8 + ot)*8 + ck))<<9) + (size_t)lane2*8 + j;
        _Float16 h1,l1; split_f16(xre,h1,l1);
        _Float16 h2,l2; split_f16(xim,h2,l2);
        Xfh[off] = h1; Xfh[off+1] = h2;
        Xfl[off] = l1; Xfl[off+1] = l2;
    }
}

// ---------------- fused in-place layer: conv via LDS (5 barriers), irfft fully direct ----------------
__global__ __launch_bounds__(256) void k_flayer(
    const _Float16* __restrict__ Xfh, const _Float16* __restrict__ Xfl,
    const _Float16* __restrict__ Tifh, const _Float16* __restrict__ Tifl,
    const _Float16* __restrict__ cWfh, const _Float16* __restrict__ cWfl,
    const float* __restrict__ convB,
    _Float16* __restrict__ hh, _Float16* __restrict__ hl,
    int layer, int applyGelu){
    __shared__ _Float16 Bs_h[2][64][40], Bs_l[2][64][40];   // 20,480 B total
    int n0 = blockIdx.x*64;
    int b  = blockIdx.y;
    int tid = threadIdx.x, lane = tid & 63, w = tid >> 6;
    int l15 = lane & 15, l4 = lane >> 4;
    int o0 = w*32;
    int ctc = tid >> 3, ctn = tid & 7;
    int ocp = ((tid >> 6) ^ (tid & 3));
    const _Float16* hB_h = hh + ((size_t)(b*128 + ctc))*4096 + n0 + ctn*8;
    const _Float16* hB_l = hl + ((size_t)(b*128 + ctc))*4096 + n0 + ctn*8;
    f32x4 acc[2][4] = {}; f32x4 acc2[2][4] = {};
    // preload ALL conv-A fragments (4 chunks x 2 otiles, h+l) — 64 VGPR
    half8 cah[4][2], cal[4][2];
    #pragma unroll
    for (int ck=0;ck<4;ck++)
        #pragma unroll
        for (int i=0;i<2;i++){
            size_t off = (((size_t)((layer*8 + w*2 + i)*4 + ck))<<9) + (size_t)lane*8;
            cah[ck][i] = *reinterpret_cast<const half8*>(cWfh + off);
            cal[ck][i] = *reinterpret_cast<const half8*>(cWfl + off);
        }
#define WRITEB(bh_,bl_,buf) do{ \
    _Pragma("unroll") for (int j2=0;j2<8;j2++){ \
        int n1 = ctn*8 + j2; \
        Bs_h[buf][n1][ocp*8 + (ctc&7)] = bh_[j2]; \
        Bs_l[buf][n1][ocp*8 + (ctc&7)] = bl_[j2]; } }while(0)
    half8 rbh = *reinterpret_cast<const half8*>(hB_h);
    half8 rbl = *reinterpret_cast<const half8*>(hB_l);
    WRITEB(rbh,rbl,0);
    rbh = *reinterpret_cast<const half8*>(hB_h + (size_t)32*4096);
    rbl = *reinterpret_cast<const half8*>(hB_l + (size_t)32*4096);
    __syncthreads();
    // ---- conv phase: 4 chunks, LDS B dbuf, 1 barrier/chunk ----
    #pragma unroll
    for (int ck=0;ck<4;ck++){
        half8 bh[4], bl[4];
        #pragma unroll
        for (int j=0;j<4;j++){
            int n = j*16 + l15; int sl = (l4 ^ ((n>>3)&3));
            bh[j] = *reinterpret_cast<const half8*>(&Bs_h[ck&1][n][sl*8]);
            bl[j] = *reinterpret_cast<const half8*>(&Bs_l[ck&1][n][sl*8]);
        }
        #pragma unroll
        for (int i=0;i<2;i++)
            #pragma unroll
            for (int j=0;j<4;j++){
                acc[i][j]  = __builtin_amdgcn_mfma_f32_16x16x32_f16(cah[ck][i], bh[j], acc[i][j], 0,0,0);
                acc2[i][j] = __builtin_amdgcn_mfma_f32_16x16x32_f16(cah[ck][i], bl[j], acc2[i][j],0,0,0);
                acc2[i][j] = __builtin_amdgcn_mfma_f32_16x16x32_f16(cal[ck][i], bh[j], acc2[i][j],0,0,0);
            }
        if (ck<3) WRITEB(rbh,rbl,(ck+1)&1);
        if (ck<2){
            rbh = *reinterpret_cast<const half8*>(hB_h + (size_t)(ck+2)*32*4096);
            rbl = *reinterpret_cast<const half8*>(hB_l + (size_t)(ck+2)*32*4096);
        }
        __syncthreads();
    }
#undef WRITEB
    // ---- irfft phase: 8 chunks, A and B direct packed fragments, ZERO barriers ----
    int nt0 = n0 >> 4;
    half8 xah[2][2], xal[2][2], xbh[2][4], xbl[2][4];
#define LOADI(s,ck) do{ \
    _Pragma("unroll") for (int i=0;i<2;i++){ \
        size_t off = (((size_t)((b*8 + w*2 + i)*8 + (ck)))<<9) + (size_t)lane*8; \
        xah[s][i] = *reinterpret_cast<const half8*>(Xfh + off); \
        xal[s][i] = *reinterpret_cast<const half8*>(Xfl + off); } \
    _Pragma("unroll") for (int j=0;j<4;j++){ \
        size_t off = (((size_t)((nt0 + j)*8 + (ck)))<<9) + (size_t)lane*8; \
        xbh[s][j] = *reinterpret_cast<const half8*>(Tifh + off); \
        xbl[s][j] = *reinterpret_cast<const half8*>(Tifl + off); } }while(0)
    LOADI(0,0); LOADI(1,1);
    #pragma unroll
    for (int ck=0;ck<8;ck++){
        const int s = ck&1;
        #pragma unroll
        for (int i=0;i<2;i++)
            #pragma unroll
            for (int j=0;j<4;j++){
                acc[i][j]  = __builtin_amdgcn_mfma_f32_16x16x32_f16(xah[s][i], xbh[s][j], acc[i][j], 0,0,0);
                acc2[i][j] = __builtin_amdgcn_mfma_f32_16x16x32_f16(xah[s][i], xbl[s][j], acc2[i][j],0,0,0);
                acc2[i][j] = __builtin_amdgcn_mfma_f32_16x16x32_f16(xal[s][i], xbh[s][j], acc2[i][j],0,0,0);
            }
        if (ck+2 < 8) LOADI(s, ck+2);
    }
#undef LOADI
    // epilogue: bias (+gelu), split, write back in place
    #pragma unroll
    for (int i=0;i<2;i++)
        #pragma unroll
        for (int j=0;j<4;j++)
            #pragma unroll
            for (int r=0;r<4;r++){
                int o = o0 + i*16 + l4*4 + r;
                int n = n0 + j*16 + l15;
                float v = acc[i][j][r] + acc2[i][j][r]*LO_INV + convB[layer*128+o];
                if (applyGelu) v = gelu_f(v);
                _Float16 hi,lo; split_f16(v,hi,lo);
                size_t oi = ((size_t)(b*128+o))*4096 + n;
                hh[oi] = hi; hl[oi] = lo;
            }
}

// ---------------- head (MFMA) ----------------
__global__ __launch_bounds__(256) void k_head(
        const _Float16* __restrict__ hh, const _Float16* __restrict__ hl,
        const _Float16* __restrict__ f1h, const _Float16* __restrict__ f1l,
        const float* __restrict__ fc1b,
        const float* __restrict__ fc2W, const float* __restrict__ fc2b,
        float* __restrict__ out){
    __shared__ _Float16 Bch[64][136], Bcl[64][136];
    __shared__ _Float16 Ash[128][40], Asl[128][40];
    __shared__ float red[16][64];
    int n0 = blockIdx.x*64;
    int b  = blockIdx.y;
    int tid = threadIdx.x, lane = tid & 63, w = tid >> 6;
    int l15 = lane & 15, l4 = lane >> 4;
    int j0 = w*32;
    {
        int c = tid & 127, nh = tid >> 7;
        const _Float16* rh = hh + ((size_t)(b*128+c))*4096 + n0 + nh*32;
        const _Float16* rl = hl + ((size_t)(b*128+c))*4096 + n0 + nh*32;
        #pragma unroll
        for (int j=0;j<4;j++){
            half8 vhv = *reinterpret_cast<const half8*>(rh + j*8);
            half8 vlv = *reinterpret_cast<const half8*>(rl + j*8);
            #pragma unroll
            for (int q=0;q<8;q++){
                int n = nh*32 + j*8 + q;
                Bch[n][c] = vhv[q];
                Bcl[n][c] = vlv[q];
            }
        }
    }
    __syncthreads();
    int so2 = tid >> 2, sseg = tid & 3;
    f32x4 acc[2][4] = {}; f32x4 acc2[2][4] = {};
    for (int k0=0;k0<128;k0+=32){
        #pragma unroll
        for (int p=0;p<2;p++){
            int o = p*64 + so2;
            *reinterpret_cast<half8*>(&Ash[o][sseg*8]) =
                *reinterpret_cast<const half8*>(&f1h[(size_t)o*128 + k0 + sseg*8]);
            *reinterpret_cast<half8*>(&Asl[o][sseg*8]) =
                *reinterpret_cast<const half8*>(&f1l[(size_t)o*128 + k0 + sseg*8]);
        }
        __syncthreads();
        half8 ah[2],al[2],bh[4],bl[4];
        #pragma unroll
        for (int i=0;i<2;i++){
            ah[i] = *reinterpret_cast<const half8*>(&Ash[j0+i*16+l15][l4*8]);
            al[i] = *reinterpret_cast<const half8*>(&Asl[j0+i*16+l15][l4*8]);
        }
        #pragma unroll
        for (int j=0;j<4;j++){
            bh[j] = *reinterpret_cast<const half8*>(&Bch[j*16+l15][k0+l4*8]);
            bl[j] = *reinterpret_cast<const half8*>(&Bcl[j*16+l15][k0+l4*8]);
        }
        #pragma unroll
        for (int i=0;i<2;i++)
            #pragma unroll
            for (int j=0;j<4;j++){
                acc[i][j]  = __builtin_amdgcn_mfma_f32_16x16x32_f16(ah[i], bh[j], acc[i][j], 0,0,0);
                acc2[i][j] = __builtin_amdgcn_mfma_f32_16x16x32_f16(ah[i], bl[j], acc2[i][j],0,0,0);
                acc2[i][j] = __builtin_amdgcn_mfma_f32_16x16x32_f16(al[i], bh[j], acc2[i][j],0,0,0);
            }
        __syncthreads();
    }
    float part[4];
    #pragma unroll
    for (int j=0;j<4;j++) part[j] = 0.f;
    #pragma unroll
    for (int i=0;i<2;i++){
        #pragma unroll
        for (int r=0;r<4;r++){
            int jj = j0 + i*16 + l4*4 + r;
            float b1 = fc1b[jj];
            float w2 = fc2W[jj];
            #pragma unroll
            for (int j=0;j<4;j++){
                float v = acc[i][j][r] + acc2[i][j][r]*LO_INV + b1;
                part[j] = fmaf(w2, gelu_f(v), part[j]);
            }
        }
    }
    #pragma unroll
    for (int j=0;j<4;j++) red[w*4+l4][j*16+l15] = part[j];
    __syncthreads();
    if (tid < 64){
        float s = fc2b[0];
        #pragma unroll
        for (int r=0;r<16;r++) s += red[r][tid];
        out[((size_t)b<<12) + n0 + tid] = s;
    }
}

extern "C" void kernel_launch(void* const* d_in, const int* in_sizes, int n_in,
                              void* d_out, int out_size, void* d_ws, size_t ws_size,
                              hipStream_t stream) {
    const float* x     = (const float*)d_in[0];
    const float* fc0W  = (const float*)d_in[1];
    const float* fc0b  = (const float*)d_in[2];
    const float* gateW = (const float*)d_in[3];
    const float* gateB = (const float*)d_in[4];
    const float* wAre  = (const float*)d_in[5];
    const float* wAim  = (const float*)d_in[6];
    const float* wBre  = (const float*)d_in[7];
    const float* wBim  = (const float*)d_in[8];
    const float* convW = (const float*)d_in[9];
    const float* convB = (const float*)d_in[10];
    const float* fc1W  = (const float*)d_in[11];
    const float* fc1b  = (const float*)d_in[12];
    const float* fc2W  = (const float*)d_in[13];
    const float* fc2b  = (const float*)d_in[14];
    float* out = (float*)d_out;
    char*  wsb = (char*)d_ws;

    float* F    = (float*)(wsb + BY_F);
    float* wsum = (float*)(wsb + BY_wsum);
    float* Wcre = (float*)(wsb + BY_Wcre);
    float* Wcim = (float*)(wsb + BY_Wcim);
    float* wl   = (float*)(wsb + BY_wl);
    float* wr   = (float*)(wsb + BY_wr);
    int*   li   = (int*)(wsb + BY_li);
    float* magp = (float*)(wsb + BY_magp);
    float* gate = (float*)(wsb + BY_gate);
    _Float16* hh   = (_Float16*)(wsb + BY_hh);
    _Float16* hl   = (_Float16*)(wsb + BY_hl);
    _Float16* Tffh = (_Float16*)(wsb + BY_Tfh);
    _Float16* Tffl = (_Float16*)(wsb + BY_Tfl);
    _Float16* Tifh = (_Float16*)(wsb + BY_Tih);
    _Float16* Tifl = (_Float16*)(wsb + BY_Til);
    _Float16* Xfh  = (_Float16*)(wsb + BY_Xh);
    _Float16* Xfl  = (_Float16*)(wsb + BY_Xl);
    _Float16* cWfh = (_Float16*)(wsb + BY_cWh);
    _Float16* cWfl = (_Float16*)(wsb + BY_cWl);
    _Float16* f1h  = (_Float16*)(wsb + BY_f1h);
    _Float16* f1l  = (_Float16*)(wsb + BY_f1l);

    k_tables<<<4096, 256, 0, stream>>>(Tffh, Tffl, Tifh, Tifl);
    k_cft_tables<<<160, 128, 0, stream>>>(Wcre, Wcim, wl, wr, li);
    k_wsum<<<dim3(16384,4), 256, 0, stream>>>(wAre, wAim, wBre, wBim, wsum);
    k_wsplit<<<320, 256, 0, stream>>>(convW, fc1W, cWfh, cWfl, f1h, f1l);
    k_h0<<<16384, 256, 0, stream>>>(x, fc0W, fc0b, hh, hl);

    for (int layer=0; layer<4; layer++){
        k_cft<<<dim3(64,16), 128, 0, stream>>>(hh, hl, Wcre, Wcim, wl, wr, li, magp);
        k_gate<<<64, 128, 0, stream>>>(magp, gateW, gateB, gate, layer);
        k_fdft<<<512, 256, 0, stream>>>(hh, hl, Tffh, Tffl, F);
        k_modemix<<<dim3(64,16), 256, 0, stream>>>(F, wsum, gate, Xfh, Xfl, layer);
        k_flayer<<<dim3(64,64), 256, 0, stream>>>(Xfh, Xfl, Tifh, Tifl, cWfh, cWfl, convB,
                                                  hh, hl, layer, layer<3 ? 1:0);
    }
    k_head<<<dim3(64,64), 256, 0, stream>>>(hh, hl, f1h, f1l, fc1b, fc2W, fc2b, out);
    (void)in_sizes; (void)n_in; (void)out_size; (void)ws_size;
}

// Round 13
// 1391.608 us; speedup vs baseline: 1.0425x; 1.0425x over previous
//
#include <hip/hip_runtime.h>
#include <math.h>

#define B_SZ 64
#define WID 128
#define NPT 4096
#define MODES 128
#define LSEG 20
#define MCH 8
#define LM 160   // LSEG*MCH

typedef _Float16 half8 __attribute__((ext_vector_type(8)));
typedef float f32x4 __attribute__((ext_vector_type(4)));

#define LO_SCALE 2048.0f
#define LO_INV   (1.0f/2048.0f)

// ---------------- workspace layout (bytes), total ~161.6 MB ----------------
static constexpr size_t BY_F    = 0;                       // fp32 [8192][256]
static constexpr size_t BY_wsum = BY_F + 8388608;          // fp32 [4][4][128][128]
static constexpr size_t BY_Wcre = BY_wsum + 1048576;       // fp32 [160][128]
static constexpr size_t BY_Wcim = BY_Wcre + 81920;
static constexpr size_t BY_wl   = BY_Wcim + 81920;         // fp32 [160] (pad)
static constexpr size_t BY_wr   = BY_wl + 1024;
static constexpr size_t BY_li   = BY_wr + 1024;            // int [160]
static constexpr size_t BY_magp = BY_li + 1024;            // fp32 [64][16][128]
static constexpr size_t BY_gate = BY_magp + 524288;        // fp32 [64][128]
static constexpr size_t BY_hh   = BY_gate + 32768;         // f16 [64][128][4096] split-hi
static constexpr size_t BY_hl   = BY_hh + 67108864;        // f16 split-lo
static constexpr size_t BY_Tfh  = BY_hl + 67108864;        // f16 frag-packed fwd [16][128][64][8]
static constexpr size_t BY_Tfl  = BY_Tfh + 2097152;
static constexpr size_t BY_Tih  = BY_Tfl + 2097152;        // f16 frag-packed inv [256][8][64][8]
static constexpr size_t BY_Til  = BY_Tih + 2097152;
static constexpr size_t BY_Xh   = BY_Til + 2097152;        // f16 [64][128][256]
static constexpr size_t BY_Xl   = BY_Xh + 4194304;
static constexpr size_t BY_cWh  = BY_Xl + 4194304;         // f16 [4][128][128]
static constexpr size_t BY_cWl  = BY_cWh + 131072;
static constexpr size_t BY_f1h  = BY_cWl + 131072;         // f16 [128][128]
static constexpr size_t BY_f1l  = BY_f1h + 32768;
static constexpr size_t BY_end  = BY_f1l + 32768;

__device__ __forceinline__ float gelu_f(float x){
    return 0.5f*x*(1.0f+erff(x*0.70710678118654752f));
}
__device__ __forceinline__ void split_f16(float v, _Float16& hi, _Float16& lo){
    hi = (_Float16)v;
    lo = (_Float16)((v - (float)hi)*LO_SCALE);
}

// ---------------- tables (split f16, MFMA-fragment-packed) ----------------
__global__ void k_tables(_Float16* __restrict__ Tffh, _Float16* __restrict__ Tffl,
                         _Float16* __restrict__ Tifh, _Float16* __restrict__ Tifl){
    int idx = blockIdx.x*256 + threadIdx.x;   // 4096*256
    int n = idx >> 8, k2 = idx & 255;
    int f = k2 >> 1;
    int m = (n*f) & 4095;
    double th = (double)m * (3.14159265358979323846/2048.0);
    double s, c; sincos(th, &s, &c);
    float vf = (k2&1) ? (float)(-s) : (float)c;
    {
        _Float16 h1,l1; split_f16(vf, h1, l1);
        int ct = k2>>4, ck = n>>5;
        int lane = (((n>>3)&3)<<4) | (k2&15);
        int j = n & 7;
        size_t off = (((size_t)(ct*128 + ck))<<9) + lane*8 + j;
        Tffh[off] = h1; Tffl[off] = l1;
    }
    float vi;
    if (k2 == 0)      vi = 1.0f;
    else if (k2 == 1) vi = 0.0f;
    else              vi = vf;
    {
        _Float16 h2,l2; split_f16(vi, h2, l2);
        int nt = n>>4, ck2 = k2>>5;
        int lane = (((k2>>3)&3)<<4) | (n&15);
        int j = k2 & 7;
        size_t off = (((size_t)(nt*8 + ck2))<<9) + lane*8 + j;
        Tifh[off] = h2; Tifl[off] = l2;
    }
}

__global__ void k_cft_tables(float* __restrict__ Wre, float* __restrict__ Wim,
                             float* __restrict__ wl, float* __restrict__ wr,
                             int* __restrict__ li){
    int idx = blockIdx.x*128 + threadIdx.x;   // 160*128
    if (idx >= LM*MODES) return;
    int lm = idx >> 7;  int f = idx & 127;
    int l = lm / MCH, m = lm % MCH;
    const double PI = 3.14159265358979323846;
    double nodes[8], Tm[8];
    #pragma unroll
    for (int j=0;j<8;j++){
        nodes[j] = -cos((2.0*j+1.0)*PI/16.0);
        Tm[j] = cos((double)m * acos(nodes[j]));
    }
    double wp = (double)f * PI * 0.05;
    double cwre=0.0, cwim=0.0;
    #pragma unroll
    for (int j=0;j<8;j++){
        double sj, cj; sincos(nodes[j]*wp, &sj, &cj);
        cwre += Tm[j]*cj;
        cwim -= Tm[j]*sj;
    }
    cwre *= 0.025; cwim *= 0.025;
    int r = (f*l) % 20;
    double sa = 2.0*PI*(double)r/20.0;
    double shre = cos(sa), shim = -sin(sa);
    Wre[lm*128+f] = (float)(shre*cwre - shim*cwim);
    Wim[lm*128+f] = (float)(shre*cwim + shim*cwre);
    if (f == 0){
        double v = (double)l/20.0 + 0.025*(nodes[m]+1.0);
        int rr = (int)ceil(v*4095.0);
        if (rr > 4095) rr = 4095;
        if (rr < 1) rr = 1;
        int le = rr-1;
        double tl = (double)le/4095.0, tr = (double)rr/4095.0;
        double wrv = (v - tl)/(tr - tl);
        li[lm] = le;
        wl[lm] = (float)(1.0 - wrv);
        wr[lm] = (float)wrv;
    }
}

// sum wA/wB over mode axis
__global__ void k_wsum(const float* __restrict__ wAre, const float* __restrict__ wAim,
                       const float* __restrict__ wBre, const float* __restrict__ wBim,
                       float* __restrict__ out){
    int row  = blockIdx.x*4 + (threadIdx.x>>6);
    int lane = threadIdx.x & 63;
    const float* src = (blockIdx.y==0)?wAre:(blockIdx.y==1)?wAim:(blockIdx.y==2)?wBre:wBim;
    float v = src[(size_t)row*128 + lane] + src[(size_t)row*128 + 64 + lane];
    #pragma unroll
    for (int o=32;o>0;o>>=1) v += __shfl_down(v, o);
    if (lane==0) out[(size_t)blockIdx.y*65536 + row] = v;
}

// pre-split conv & fc1 weights (linear layouts)
__global__ void k_wsplit(const float* __restrict__ convW, const float* __restrict__ fc1W,
                         _Float16* __restrict__ cWh, _Float16* __restrict__ cWl,
                         _Float16* __restrict__ f1h, _Float16* __restrict__ f1l){
    int idx = blockIdx.x*256 + threadIdx.x;   // 81920
    if (idx < 65536){
        _Float16 hi,lo; split_f16(convW[idx], hi, lo);
        cWh[idx]=hi; cWl[idx]=lo;
    } else {
        int j = idx - 65536;
        _Float16 hi,lo; split_f16(fc1W[j], hi, lo);
        f1h[j]=hi; f1l[j]=lo;
    }
}

// ---------------- lift: write split h ----------------
__global__ void k_h0(const float* __restrict__ x, const float* __restrict__ w0,
                     const float* __restrict__ b0,
                     _Float16* __restrict__ hh, _Float16* __restrict__ hl){
    int idx = blockIdx.x*256 + threadIdx.x;  // 64*128*512
    int n8 = idx & 511;
    int w  = (idx >> 9) & 127;
    int b  = idx >> 16;
    int n0 = n8*8;
    float w00 = w0[w*2], w01 = w0[w*2+1], bb = b0[w];
    const float* xr = &x[((size_t)b<<12) + n0];
    float4 x0 = *reinterpret_cast<const float4*>(xr);
    float4 x1 = *reinterpret_cast<const float4*>(xr+4);
    float xv[8]={x0.x,x0.y,x0.z,x0.w,x1.x,x1.y,x1.z,x1.w};
    half8 vh, vl;
    #pragma unroll
    for (int q=0;q<8;q++){
        float g = (float)(n0+q) * (1.0f/4095.0f);
        float v = xv[q]*w00 + g*w01 + bb;
        _Float16 hi,lo; split_f16(v,hi,lo);
        vh[q]=hi; vl[q]=lo;
    }
    size_t o = ((size_t)(b*128+w))*4096 + n0;
    *reinterpret_cast<half8*>(&hh[o]) = vh;
    *reinterpret_cast<half8*>(&hl[o]) = vl;
}

// ---------------- CFT magnitude (16 groups of 8 channels) ----------------
__global__ void k_cft(const _Float16* __restrict__ hh, const _Float16* __restrict__ hl,
                      const float* __restrict__ Wre, const float* __restrict__ Wim,
                      const float* __restrict__ wl, const float* __restrict__ wr,
                      const int* __restrict__ li, float* __restrict__ magp){
    int b = blockIdx.x, cg = blockIdx.y;
    int f = threadIdx.x;   // 128
    __shared__ float sig[LM];
    __shared__ float swl[LM], swr[LM];
    __shared__ int   sli[LM];
    for (int s=f; s<LM; s+=128){ swl[s]=wl[s]; swr[s]=wr[s]; sli[s]=li[s]; }
    __syncthreads();
    float acc = 0.f;
    for (int cc=0; cc<8; cc++){
        int c = cg*8 + cc;
        const _Float16* rh = hh + ((size_t)(b*128+c))*4096;
        const _Float16* rl = hl + ((size_t)(b*128+c))*4096;
        for (int s=f; s<LM; s+=128){
            int le = sli[s];
            float v0 = (float)rh[le]   + (float)rl[le]*LO_INV;
            float v1 = (float)rh[le+1] + (float)rl[le+1]*LO_INV;
            sig[s] = swl[s]*v0 + swr[s]*v1;
        }
        __syncthreads();
        float re=0.f, im=0.f;
        #pragma unroll 8
        for (int s=0;s<LM;s++){
            float sv = sig[s];
            re = fmaf(sv, Wre[s*128+f], re);
            im = fmaf(sv, Wim[s*128+f], im);
        }
        acc += sqrtf(re*re+im*im);
        __syncthreads();
    }
    magp[(b*16+cg)*128 + f] = acc;
}

__global__ void k_gate(const float* __restrict__ magp, const float* __restrict__ gW,
                       const float* __restrict__ gB, float* __restrict__ gate, int layer){
    int b = blockIdx.x, w = threadIdx.x;
    __shared__ float ms[128];
    float s = 0.f;
    #pragma unroll
    for (int g=0; g<16; g++) s += magp[(b*16+g)*128 + w];
    ms[w] = s * (1.0f/128.0f);
    __syncthreads();
    const float* gwr = gW + ((size_t)layer*128 + w)*128;
    float a = gB[layer*128 + w];
    #pragma unroll 8
    for (int fq=0; fq<128; fq++) a = fmaf(ms[fq], gwr[fq], a);
    gate[b*128+w] = 1.0f/(1.0f+expf(-a));
}

// ---------------- forward DFT: A-only LDS dbuf (stride 34), B direct packed fragments ----------------
__global__ __launch_bounds__(256) void k_fdft(
        const _Float16* __restrict__ hh, const _Float16* __restrict__ hl,
        const _Float16* __restrict__ Tffh, const _Float16* __restrict__ Tffl,
        float* __restrict__ F){
    __shared__ _Float16 Ah[2][64][34], Al[2][64][34];
    int id = blockIdx.x;
    int swz = (id & 7)*64 + (id >> 3);        // bijective for 512
    int bx = swz & 3, by = swz >> 2;
    int col0 = bx*64, row0 = by*64;
    int tid = threadIdx.x, lane = tid & 63, w = tid >> 6;
    int wr = (w>>1)*32, wc = (w&1)*32;
    int l15 = lane & 15, l4 = lane >> 4;
    f32x4 acc[2][2] = {}; f32x4 acc2[2][2] = {};
    int srow = tid >> 2, sseg = tid & 3;
    const _Float16* pa_h = hh + (size_t)(row0+srow)*4096 + sseg*8;
    const _Float16* pa_l = hl + (size_t)(row0+srow)*4096 + sseg*8;
    int ct0 = (col0 + wc) >> 4;
    const _Float16* pfh = Tffh + (size_t)lane*8;
    const _Float16* pfl = Tffl + (size_t)lane*8;
    half8 a0h,a0l,a1h,a1l;
    half8 bf0[4], bf1[4];
#define LOADA(xh,xl,ck) do{ \
    xh = *reinterpret_cast<const half8*>(pa_h + (size_t)(ck)*32); \
    xl = *reinterpret_cast<const half8*>(pa_l + (size_t)(ck)*32); }while(0)
#define WRITEA(xh,xl,buf) do{ \
    *reinterpret_cast<half8*>(&Ah[buf][srow][sseg*8]) = xh; \
    *reinterpret_cast<half8*>(&Al[buf][srow][sseg*8]) = xl; }while(0)
#define LOADB(dst,ck) do{ \
    dst[0] = *reinterpret_cast<const half8*>(pfh + (((size_t)(ct0  )*128 + (ck))<<9)); \
    dst[1] = *reinterpret_cast<const half8*>(pfh + (((size_t)(ct0+1)*128 + (ck))<<9)); \
    dst[2] = *reinterpret_cast<const half8*>(pfl + (((size_t)(ct0  )*128 + (ck))<<9)); \
    dst[3] = *reinterpret_cast<const half8*>(pfl + (((size_t)(ct0+1)*128 + (ck))<<9)); }while(0)
#define MMF(buf,BF) do{ \
    _Pragma("unroll") for (int i=0;i<2;i++){ \
        half8 fah = *reinterpret_cast<const half8*>(&Ah[buf][wr + i*16 + l15][l4*8]); \
        half8 fal = *reinterpret_cast<const half8*>(&Al[buf][wr + i*16 + l15][l4*8]); \
        _Pragma("unroll") for (int j=0;j<2;j++){ \
            acc[i][j]  = __builtin_amdgcn_mfma_f32_16x16x32_f16(fah, BF[j],   acc[i][j], 0,0,0); \
            acc2[i][j] = __builtin_amdgcn_mfma_f32_16x16x32_f16(fah, BF[2+j], acc2[i][j],0,0,0); \
            acc2[i][j] = __builtin_amdgcn_mfma_f32_16x16x32_f16(fal, BF[j],   acc2[i][j],0,0,0); } } }while(0)
    LOADA(a0h,a0l,0); WRITEA(a0h,a0l,0);
    LOADA(a0h,a0l,1);
    LOADA(a1h,a1l,2);
    LOADB(bf0,0); LOADB(bf1,1);
    __syncthreads();
    for (int tt=0; tt<64; ++tt){
        int t = tt*2;
        MMF(0,bf0);
        WRITEA(a0h,a0l,1);                  // chunk t+1
        if (t+2 < 128) LOADB(bf0, t+2);
        if (t+3 < 128) LOADA(a0h,a0l, t+3);
        __syncthreads();
        MMF(1,bf1);
        if (t+2 < 128) WRITEA(a1h,a1l,0);   // chunk t+2
        if (t+3 < 128) LOADB(bf1, t+3);
        if (t+4 < 128) LOADA(a1h,a1l, t+4);
        __syncthreads();
    }
#undef LOADA
#undef WRITEA
#undef LOADB
#undef MMF
    #pragma unroll
    for (int i=0;i<2;i++)
        #pragma unroll
        for (int j=0;j<2;j++)
            #pragma unroll
            for (int r=0;r<4;r++){
                int row = row0 + wr + i*16 + l4*4 + r;
                int col = col0 + wc + j*16 + l15;
                F[(size_t)row*256 + col] = acc[i][j][r] + acc2[i][j][r]*LO_INV;
            }
}

// ---------------- mode mix: X = g*(F.wA) + (1-g)*(F.wB), scaled, split ----------------
__global__ __launch_bounds__(256) void k_modemix(const float* __restrict__ F,
        const float* __restrict__ wsum, const float* __restrict__ gate,
        _Float16* __restrict__ Xh, _Float16* __restrict__ Xl, int layer){
    int b = blockIdx.x, og = blockIdx.y;
    __shared__ float Fs[16][256];
    __shared__ float Wa_re[128][8], Wa_im[128][8], Wb_re[128][8], Wb_im[128][8];
    int tid = threadIdx.x;
    for (int e=tid; e<1024; e+=256){
        int i = e>>3, oo = e&7;
        size_t base = ((size_t)layer*128 + i)*128 + og*8 + oo;
        Wa_re[i][oo] = wsum[0*65536 + base];
        Wa_im[i][oo] = wsum[1*65536 + base];
        Wb_re[i][oo] = wsum[2*65536 + base];
        Wb_im[i][oo] = wsum[3*65536 + base];
    }
    int f = tid & 127, half = tid >> 7;
    float pre[4]={},pim[4]={},qre[4]={},qim[4]={};
    for (int i0=0;i0<128;i0+=16){
        for (int e=tid; e<4096; e+=256){
            int ii = e >> 8, k2 = e & 255;
            Fs[ii][k2] = F[((size_t)(b*128 + i0+ii))*256 + k2];
        }
        __syncthreads();
        #pragma unroll
        for (int ii=0; ii<16; ii++){
            float fre = Fs[ii][2*f], fim = Fs[ii][2*f+1];
            int i = i0+ii;
            #pragma unroll
            for (int q=0;q<4;q++){
                int oo = half*4+q;
                float are=Wa_re[i][oo], aim=Wa_im[i][oo];
                float bre=Wb_re[i][oo], bim=Wb_im[i][oo];
                pre[q] = fmaf(fre, are, fmaf(-fim, aim, pre[q]));
                pim[q] = fmaf(fre, aim, fmaf( fim, are, pim[q]));
                qre[q] = fmaf(fre, bre, fmaf(-fim, bim, qre[q]));
                qim[q] = fmaf(fre, bim, fmaf( fim, bre, qim[q]));
            }
        }
        __syncthreads();
    }
    #pragma unroll
    for (int q=0;q<4;q++){
        int o = og*8 + half*4 + q;
        float g = gate[b*128+o];
        float xre = g*pre[q] + (1.f-g)*qre[q];
        float xim = g*pim[q] + (1.f-g)*qim[q];
        float s = (f==0) ? (1.0f/4096.0f) : (2.0f/4096.0f);
        xre *= s; xim *= s;
        if (f==0) xim = 0.f;
        size_t base = ((size_t)(b*128+o))*256 + 2*f;
        _Float16 h1,l1; split_f16(xre,h1,l1); Xh[base]=h1;   Xl[base]=l1;
        _Float16 h2,l2; split_f16(xim,h2,l2); Xh[base+1]=h2; Xl[base+1]=l2;
    }
}

// ---------------- fused in-place layer: 12-chunk pipeline; Ti via packed fragments ----------------
// chunks 0..3: conv (A=convW LDS, B=transposed h LDS XOR-swizzled);
// chunks 4..11: irfft (A=X LDS, B=Ti direct-global packed fragments in bf0/bf1).
// LDS stride 34 halves -> 52,224 B -> 3 blocks/CU.
__global__ __launch_bounds__(256) void k_flayer(
    const _Float16* __restrict__ Xh, const _Float16* __restrict__ Xl,
    const _Float16* __restrict__ Tifh, const _Float16* __restrict__ Tifl,
    const _Float16* __restrict__ cWh, const _Float16* __restrict__ cWl,
    const float* __restrict__ convB,
    _Float16* __restrict__ hh, _Float16* __restrict__ hl,
    int layer, int applyGelu){
    __shared__ _Float16 As_h[2][128][34], As_l[2][128][34];   // 34,816 B
    __shared__ _Float16 Bs_h[2][64][34],  Bs_l[2][64][34];    // 17,408 B (conv only)
    int n0 = blockIdx.x*64;
    int b  = blockIdx.y;
    int tid = threadIdx.x, lane = tid & 63, w = tid >> 6;
    int l15 = lane & 15, l4 = lane >> 4;
    int o0 = w*32;
    int aro = tid >> 2, asl = tid & 3;
    int ctc = tid >> 3, ctn = tid & 7;          // conv-B: local c, n-octet
    int ocp = ((tid >> 6) ^ (tid & 3));         // conv-B write octet (swizzled)
    const _Float16* cA_h = cWh + (size_t)layer*16384 + (size_t)aro*128 + asl*8;
    const _Float16* cA_l = cWl + (size_t)layer*16384 + (size_t)aro*128 + asl*8;
    const _Float16* xA_h = Xh + ((size_t)(b*128 + aro))*256 + asl*8;
    const _Float16* xA_l = Xl + ((size_t)(b*128 + aro))*256 + asl*8;
    const _Float16* hB_h = hh + ((size_t)(b*128 + ctc))*4096 + n0 + ctn*8;
    const _Float16* hB_l = hl + ((size_t)(b*128 + ctc))*4096 + n0 + ctn*8;
    int nt0 = n0 >> 4;
    const _Float16* pTh = Tifh + (size_t)lane*8;
    const _Float16* pTl = Tifl + (size_t)lane*8;
    f32x4 acc[2][4] = {}; f32x4 acc2[2][4] = {};
    half8 rA[6], rB[6];
    half8 bf0[8], bf1[8];
#define LOADR(r,ck) do{ \
    if ((ck) < 4){ size_t kk = (size_t)(ck)*32; \
        r[0] = *reinterpret_cast<const half8*>(cA_h + kk); \
        r[1] = *reinterpret_cast<const half8*>(cA_l + kk); \
        r[2] = *reinterpret_cast<const half8*>(cA_h + 64*128 + kk); \
        r[3] = *reinterpret_cast<const half8*>(cA_l + 64*128 + kk); \
        r[4] = *reinterpret_cast<const half8*>(hB_h + (size_t)(ck)*32*4096); \
        r[5] = *reinterpret_cast<const half8*>(hB_l + (size_t)(ck)*32*4096); \
    } else { size_t kk = (size_t)((ck)-4)*32; \
        r[0] = *reinterpret_cast<const half8*>(xA_h + kk); \
        r[1] = *reinterpret_cast<const half8*>(xA_l + kk); \
        r[2] = *reinterpret_cast<const half8*>(xA_h + 64*256 + kk); \
        r[3] = *reinterpret_cast<const half8*>(xA_l + 64*256 + kk); } }while(0)
#define WRITER(r,buf,ck) do{ \
    *reinterpret_cast<half8*>(&As_h[buf][aro][asl*8])    = r[0]; \
    *reinterpret_cast<half8*>(&As_l[buf][aro][asl*8])    = r[1]; \
    *reinterpret_cast<half8*>(&As_h[buf][aro+64][asl*8]) = r[2]; \
    *reinterpret_cast<half8*>(&As_l[buf][aro+64][asl*8]) = r[3]; \
    if ((ck) < 4){ \
        _Pragma("unroll") for (int j2=0;j2<8;j2++){ \
            int n1 = ctn*8 + j2; \
            Bs_h[buf][n1][ocp*8 + (ctc&7)] = r[4][j2]; \
            Bs_l[buf][n1][ocp*8 + (ctc&7)] = r[5][j2]; } } }while(0)
#define LOADBF(dst,ckp) do{ \
    _Pragma("unroll") for (int j=0;j<4;j++){ \
        dst[j]   = *reinterpret_cast<const half8*>(pTh + (((size_t)((nt0+j)*8 + (ckp)))<<9)); \
        dst[4+j] = *reinterpret_cast<const half8*>(pTl + (((size_t)((nt0+j)*8 + (ckp)))<<9)); } }while(0)
#define MML(buf,ck,BF) do{ \
    half8 bh[4], bl[4]; \
    if ((ck) < 4){ \
        _Pragma("unroll") for (int j=0;j<4;j++){ \
            int n = j*16 + l15; int sl = (l4 ^ ((n>>3)&3)); \
            bh[j] = *reinterpret_cast<const half8*>(&Bs_h[buf][n][sl*8]); \
            bl[j] = *reinterpret_cast<const half8*>(&Bs_l[buf][n][sl*8]); } \
    } else { \
        _Pragma("unroll") for (int j=0;j<4;j++){ bh[j] = BF[j]; bl[j] = BF[4+j]; } } \
    _Pragma("unroll") for (int i=0;i<2;i++){ \
        half8 ah = *reinterpret_cast<const half8*>(&As_h[buf][o0+i*16+l15][l4*8]); \
        half8 al = *reinterpret_cast<const half8*>(&As_l[buf][o0+i*16+l15][l4*8]); \
        _Pragma("unroll") for (int j=0;j<4;j++){ \
            acc[i][j]  = __builtin_amdgcn_mfma_f32_16x16x32_f16(ah, bh[j], acc[i][j], 0,0,0); \
            acc2[i][j] = __builtin_amdgcn_mfma_f32_16x16x32_f16(ah, bl[j], acc2[i][j],0,0,0); \
            acc2[i][j] = __builtin_amdgcn_mfma_f32_16x16x32_f16(al, bh[j], acc2[i][j],0,0,0); } } }while(0)
    LOADR(rA, 0);
    WRITER(rA, 0, 0);
    LOADR(rA, 1);
    LOADR(rB, 2);
    __syncthreads();
    #pragma unroll
    for (int tt=0; tt<6; ++tt){
        const int t = 2*tt;
        MML(0, t, bf0);
        WRITER(rA, 1, t+1);
        if (t+2 >= 4 && t+2 < 12) LOADBF(bf0, t+2-4);
        if (t+3 < 12) LOADR(rA, t+3);
        __syncthreads();
        MML(1, t+1, bf1);
        if (t+2 < 12) WRITER(rB, 0, t+2);
        if (t+3 >= 4 && t+3 < 12) LOADBF(bf1, t+3-4);
        if (t+4 < 12) LOADR(rB, t+4);
        __syncthreads();
    }
#undef LOADR
#undef WRITER
#undef LOADBF
#undef MML
    // epilogue: bias (+gelu), split, write back in place
    #pragma unroll
    for (int i=0;i<2;i++)
        #pragma unroll
        for (int j=0;j<4;j++)
            #pragma unroll
            for (int r=0;r<4;r++){
                int o = o0 + i*16 + l4*4 + r;
                int n = n0 + j*16 + l15;
                float v = acc[i][j][r] + acc2[i][j][r]*LO_INV + convB[layer*128+o];
                if (applyGelu) v = gelu_f(v);
                _Float16 hi,lo; split_f16(v,hi,lo);
                size_t oi = ((size_t)(b*128+o))*4096 + n;
                hh[oi] = hi; hl[oi] = lo;
            }
}

// ---------------- head (MFMA) ----------------
__global__ __launch_bounds__(256) void k_head(
        const _Float16* __restrict__ hh, const _Float16* __restrict__ hl,
        const _Float16* __restrict__ f1h, const _Float16* __restrict__ f1l,
        const float* __restrict__ fc1b,
        const float* __restrict__ fc2W, const float* __restrict__ fc2b,
        float* __restrict__ out){
    __shared__ _Float16 Bch[64][136], Bcl[64][136];
    __shared__ _Float16 Ash[128][40], Asl[128][40];
    __shared__ float red[16][64];
    int n0 = blockIdx.x*64;
    int b  = blockIdx.y;
    int tid = threadIdx.x, lane = tid & 63, w = tid >> 6;
    int l15 = lane & 15, l4 = lane >> 4;
    int j0 = w*32;
    {
        int c = tid & 127, nh = tid >> 7;
        const _Float16* rh = hh + ((size_t)(b*128+c))*4096 + n0 + nh*32;
        const _Float16* rl = hl + ((size_t)(b*128+c))*4096 + n0 + nh*32;
        #pragma unroll
        for (int j=0;j<4;j++){
            half8 vhv = *reinterpret_cast<const half8*>(rh + j*8);
            half8 vlv = *reinterpret_cast<const half8*>(rl + j*8);
            #pragma unroll
            for (int q=0;q<8;q++){
                int n = nh*32 + j*8 + q;
                Bch[n][c] = vhv[q];
                Bcl[n][c] = vlv[q];
            }
        }
    }
    __syncthreads();
    int so2 = tid >> 2, sseg = tid & 3;
    f32x4 acc[2][4] = {}; f32x4 acc2[2][4] = {};
    for (int k0=0;k0<128;k0+=32){
        #pragma unroll
        for (int p=0;p<2;p++){
            int o = p*64 + so2;
            *reinterpret_cast<half8*>(&Ash[o][sseg*8]) =
                *reinterpret_cast<const half8*>(&f1h[(size_t)o*128 + k0 + sseg*8]);
            *reinterpret_cast<half8*>(&Asl[o][sseg*8]) =
                *reinterpret_cast<const half8*>(&f1l[(size_t)o*128 + k0 + sseg*8]);
        }
        __syncthreads();
        half8 ah[2],al[2],bh[4],bl[4];
        #pragma unroll
        for (int i=0;i<2;i++){
            ah[i] = *reinterpret_cast<const half8*>(&Ash[j0+i*16+l15][l4*8]);
            al[i] = *reinterpret_cast<const half8*>(&Asl[j0+i*16+l15][l4*8]);
        }
        #pragma unroll
        for (int j=0;j<4;j++){
            bh[j] = *reinterpret_cast<const half8*>(&Bch[j*16+l15][k0+l4*8]);
            bl[j] = *reinterpret_cast<const half8*>(&Bcl[j*16+l15][k0+l4*8]);
        }
        #pragma unroll
        for (int i=0;i<2;i++)
            #pragma unroll
            for (int j=0;j<4;j++){
                acc[i][j]  = __builtin_amdgcn_mfma_f32_16x16x32_f16(ah[i], bh[j], acc[i][j], 0,0,0);
                acc2[i][j] = __builtin_amdgcn_mfma_f32_16x16x32_f16(ah[i], bl[j], acc2[i][j],0,0,0);
                acc2[i][j] = __builtin_amdgcn_mfma_f32_16x16x32_f16(al[i], bh[j], acc2[i][j],0,0,0);
            }
        __syncthreads();
    }
    float part[4];
    #pragma unroll
    for (int j=0;j<4;j++) part[j] = 0.f;
    #pragma unroll
    for (int i=0;i<2;i++){
        #pragma unroll
        for (int r=0;r<4;r++){
            int jj = j0 + i*16 + l4*4 + r;
            float b1 = fc1b[jj];
            float w2 = fc2W[jj];
            #pragma unroll
            for (int j=0;j<4;j++){
                float v = acc[i][j][r] + acc2[i][j][r]*LO_INV + b1;
                part[j] = fmaf(w2, gelu_f(v), part[j]);
            }
        }
    }
    #pragma unroll
    for (int j=0;j<4;j++) red[w*4+l4][j*16+l15] = part[j];
    __syncthreads();
    if (tid < 64){
        float s = fc2b[0];
        #pragma unroll
        for (int r=0;r<16;r++) s += red[r][tid];
        out[((size_t)b<<12) + n0 + tid] = s;
    }
}

extern "C" void kernel_launch(void* const* d_in, const int* in_sizes, int n_in,
                              void* d_out, int out_size, void* d_ws, size_t ws_size,
                              hipStream_t stream) {
    const float* x     = (const float*)d_in[0];
    const float* fc0W  = (const float*)d_in[1];
    const float* fc0b  = (const float*)d_in[2];
    const float* gateW = (const float*)d_in[3];
    const float* gateB = (const float*)d_in[4];
    const float* wAre  = (const float*)d_in[5];
    const float* wAim  = (const float*)d_in[6];
    const float* wBre  = (const float*)d_in[7];
    const float* wBim  = (const float*)d_in[8];
    const float* convW = (const float*)d_in[9];
    const float* convB = (const float*)d_in[10];
    const float* fc1W  = (const float*)d_in[11];
    const float* fc1b  = (const float*)d_in[12];
    const float* fc2W  = (const float*)d_in[13];
    const float* fc2b  = (const float*)d_in[14];
    float* out = (float*)d_out;
    char*  wsb = (char*)d_ws;

    float* F    = (float*)(wsb + BY_F);
    float* wsum = (float*)(wsb + BY_wsum);
    float* Wcre = (float*)(wsb + BY_Wcre);
    float* Wcim = (float*)(wsb + BY_Wcim);
    float* wl   = (float*)(wsb + BY_wl);
    float* wr   = (float*)(wsb + BY_wr);
    int*   li   = (int*)(wsb + BY_li);
    float* magp = (float*)(wsb + BY_magp);
    float* gate = (float*)(wsb + BY_gate);
    _Float16* hh   = (_Float16*)(wsb + BY_hh);
    _Float16* hl   = (_Float16*)(wsb + BY_hl);
    _Float16* Tffh = (_Float16*)(wsb + BY_Tfh);
    _Float16* Tffl = (_Float16*)(wsb + BY_Tfl);
    _Float16* Tifh = (_Float16*)(wsb + BY_Tih);
    _Float16* Tifl = (_Float16*)(wsb + BY_Til);
    _Float16* Xh   = (_Float16*)(wsb + BY_Xh);
    _Float16* Xl   = (_Float16*)(wsb + BY_Xl);
    _Float16* cWh  = (_Float16*)(wsb + BY_cWh);
    _Float16* cWl  = (_Float16*)(wsb + BY_cWl);
    _Float16* f1h  = (_Float16*)(wsb + BY_f1h);
    _Float16* f1l  = (_Float16*)(wsb + BY_f1l);

    k_tables<<<4096, 256, 0, stream>>>(Tffh, Tffl, Tifh, Tifl);
    k_cft_tables<<<160, 128, 0, stream>>>(Wcre, Wcim, wl, wr, li);
    k_wsum<<<dim3(16384,4), 256, 0, stream>>>(wAre, wAim, wBre, wBim, wsum);
    k_wsplit<<<320, 256, 0, stream>>>(convW, fc1W, cWh, cWl, f1h, f1l);
    k_h0<<<16384, 256, 0, stream>>>(x, fc0W, fc0b, hh, hl);

    for (int layer=0; layer<4; layer++){
        k_cft<<<dim3(64,16), 128, 0, stream>>>(hh, hl, Wcre, Wcim, wl, wr, li, magp);
        k_gate<<<64, 128, 0, stream>>>(magp, gateW, gateB, gate, layer);
        k_fdft<<<512, 256, 0, stream>>>(hh, hl, Tffh, Tffl, F);
        k_modemix<<<dim3(64,16), 256, 0, stream>>>(F, wsum, gate, Xh, Xl, layer);
        k_flayer<<<dim3(64,64), 256, 0, stream>>>(Xh, Xl, Tifh, Tifl, cWh, cWl, convB,
                                                  hh, hl, layer, layer<3 ? 1:0);
    }
    k_head<<<dim3(64,64), 256, 0, stream>>>(hh, hl, f1h, f1l, fc1b, fc2W, fc2b, out);
    (void)in_sizes; (void)n_in; (void)out_size; (void)ws_size;
}

// Round 14
// 1374.297 us; speedup vs baseline: 1.0556x; 1.0126x over previous
//
#include <hip/hip_runtime.h>
#include <math.h>

#define B_SZ 64
#define WID 128
#define NPT 4096
#define MODES 128
#define LSEG 20
#define MCH 8
#define LM 160   // LSEG*MCH

typedef _Float16 half8 __attribute__((ext_vector_type(8)));
typedef float f32x4 __attribute__((ext_vector_type(4)));

#define LO_SCALE 2048.0f
#define LO_INV   (1.0f/2048.0f)

// ---------------- workspace layout (bytes), total ~170 MB ----------------
static constexpr size_t BY_F    = 0;                       // fp32 [2 ksplit][8192][256]
static constexpr size_t BY_wsum = BY_F + 16777216;         // fp32 [4][4][128][128]
static constexpr size_t BY_Wcre = BY_wsum + 1048576;       // fp32 [160][128]
static constexpr size_t BY_Wcim = BY_Wcre + 81920;
static constexpr size_t BY_wl   = BY_Wcim + 81920;         // fp32 [160] (pad)
static constexpr size_t BY_wr   = BY_wl + 1024;
static constexpr size_t BY_li   = BY_wr + 1024;            // int [160]
static constexpr size_t BY_magp = BY_li + 1024;            // fp32 [64][16][128]
static constexpr size_t BY_gate = BY_magp + 524288;        // fp32 [64][128]
static constexpr size_t BY_hh   = BY_gate + 32768;         // f16 [64][128][4096] split-hi
static constexpr size_t BY_hl   = BY_hh + 67108864;        // f16 split-lo
static constexpr size_t BY_Tfh  = BY_hl + 67108864;        // f16 frag-packed fwd [16][128][64][8]
static constexpr size_t BY_Tfl  = BY_Tfh + 2097152;
static constexpr size_t BY_Tih  = BY_Tfl + 2097152;        // f16 frag-packed inv [256][8][64][8]
static constexpr size_t BY_Til  = BY_Tih + 2097152;
static constexpr size_t BY_Xh   = BY_Til + 2097152;        // f16 [64][128][256]
static constexpr size_t BY_Xl   = BY_Xh + 4194304;
static constexpr size_t BY_cWh  = BY_Xl + 4194304;         // f16 [4][128][128]
static constexpr size_t BY_cWl  = BY_cWh + 131072;
static constexpr size_t BY_f1h  = BY_cWl + 131072;         // f16 [128][128]
static constexpr size_t BY_f1l  = BY_f1h + 32768;
static constexpr size_t BY_end  = BY_f1l + 32768;

__device__ __forceinline__ float gelu_f(float x){
    return 0.5f*x*(1.0f+erff(x*0.70710678118654752f));
}
__device__ __forceinline__ void split_f16(float v, _Float16& hi, _Float16& lo){
    hi = (_Float16)v;
    lo = (_Float16)((v - (float)hi)*LO_SCALE);
}

// ---------------- tables (split f16, MFMA-fragment-packed) ----------------
__global__ void k_tables(_Float16* __restrict__ Tffh, _Float16* __restrict__ Tffl,
                         _Float16* __restrict__ Tifh, _Float16* __restrict__ Tifl){
    int idx = blockIdx.x*256 + threadIdx.x;   // 4096*256
    int n = idx >> 8, k2 = idx & 255;
    int f = k2 >> 1;
    int m = (n*f) & 4095;
    double th = (double)m * (3.14159265358979323846/2048.0);
    double s, c; sincos(th, &s, &c);
    float vf = (k2&1) ? (float)(-s) : (float)c;
    {
        _Float16 h1,l1; split_f16(vf, h1, l1);
        int ct = k2>>4, ck = n>>5;
        int lane = (((n>>3)&3)<<4) | (k2&15);
        int j = n & 7;
        size_t off = (((size_t)(ct*128 + ck))<<9) + lane*8 + j;
        Tffh[off] = h1; Tffl[off] = l1;
    }
    float vi;
    if (k2 == 0)      vi = 1.0f;
    else if (k2 == 1) vi = 0.0f;
    else              vi = vf;
    {
        _Float16 h2,l2; split_f16(vi, h2, l2);
        int nt = n>>4, ck2 = k2>>5;
        int lane = (((k2>>3)&3)<<4) | (n&15);
        int j = k2 & 7;
        size_t off = (((size_t)(nt*8 + ck2))<<9) + lane*8 + j;
        Tifh[off] = h2; Tifl[off] = l2;
    }
}

__global__ void k_cft_tables(float* __restrict__ Wre, float* __restrict__ Wim,
                             float* __restrict__ wl, float* __restrict__ wr,
                             int* __restrict__ li){
    int idx = blockIdx.x*128 + threadIdx.x;   // 160*128
    if (idx >= LM*MODES) return;
    int lm = idx >> 7;  int f = idx & 127;
    int l = lm / MCH, m = lm % MCH;
    const double PI = 3.14159265358979323846;
    double nodes[8], Tm[8];
    #pragma unroll
    for (int j=0;j<8;j++){
        nodes[j] = -cos((2.0*j+1.0)*PI/16.0);
        Tm[j] = cos((double)m * acos(nodes[j]));
    }
    double wp = (double)f * PI * 0.05;
    double cwre=0.0, cwim=0.0;
    #pragma unroll
    for (int j=0;j<8;j++){
        double sj, cj; sincos(nodes[j]*wp, &sj, &cj);
        cwre += Tm[j]*cj;
        cwim -= Tm[j]*sj;
    }
    cwre *= 0.025; cwim *= 0.025;
    int r = (f*l) % 20;
    double sa = 2.0*PI*(double)r/20.0;
    double shre = cos(sa), shim = -sin(sa);
    Wre[lm*128+f] = (float)(shre*cwre - shim*cwim);
    Wim[lm*128+f] = (float)(shre*cwim + shim*cwre);
    if (f == 0){
        double v = (double)l/20.0 + 0.025*(nodes[m]+1.0);
        int rr = (int)ceil(v*4095.0);
        if (rr > 4095) rr = 4095;
        if (rr < 1) rr = 1;
        int le = rr-1;
        double tl = (double)le/4095.0, tr = (double)rr/4095.0;
        double wrv = (v - tl)/(tr - tl);
        li[lm] = le;
        wl[lm] = (float)(1.0 - wrv);
        wr[lm] = (float)wrv;
    }
}

// sum wA/wB over mode axis
__global__ void k_wsum(const float* __restrict__ wAre, const float* __restrict__ wAim,
                       const float* __restrict__ wBre, const float* __restrict__ wBim,
                       float* __restrict__ out){
    int row  = blockIdx.x*4 + (threadIdx.x>>6);
    int lane = threadIdx.x & 63;
    const float* src = (blockIdx.y==0)?wAre:(blockIdx.y==1)?wAim:(blockIdx.y==2)?wBre:wBim;
    float v = src[(size_t)row*128 + lane] + src[(size_t)row*128 + 64 + lane];
    #pragma unroll
    for (int o=32;o>0;o>>=1) v += __shfl_down(v, o);
    if (lane==0) out[(size_t)blockIdx.y*65536 + row] = v;
}

// pre-split conv & fc1 weights (linear layouts)
__global__ void k_wsplit(const float* __restrict__ convW, const float* __restrict__ fc1W,
                         _Float16* __restrict__ cWh, _Float16* __restrict__ cWl,
                         _Float16* __restrict__ f1h, _Float16* __restrict__ f1l){
    int idx = blockIdx.x*256 + threadIdx.x;   // 81920
    if (idx < 65536){
        _Float16 hi,lo; split_f16(convW[idx], hi, lo);
        cWh[idx]=hi; cWl[idx]=lo;
    } else {
        int j = idx - 65536;
        _Float16 hi,lo; split_f16(fc1W[j], hi, lo);
        f1h[j]=hi; f1l[j]=lo;
    }
}

// ---------------- lift: write split h ----------------
__global__ void k_h0(const float* __restrict__ x, const float* __restrict__ w0,
                     const float* __restrict__ b0,
                     _Float16* __restrict__ hh, _Float16* __restrict__ hl){
    int idx = blockIdx.x*256 + threadIdx.x;  // 64*128*512
    int n8 = idx & 511;
    int w  = (idx >> 9) & 127;
    int b  = idx >> 16;
    int n0 = n8*8;
    float w00 = w0[w*2], w01 = w0[w*2+1], bb = b0[w];
    const float* xr = &x[((size_t)b<<12) + n0];
    float4 x0 = *reinterpret_cast<const float4*>(xr);
    float4 x1 = *reinterpret_cast<const float4*>(xr+4);
    float xv[8]={x0.x,x0.y,x0.z,x0.w,x1.x,x1.y,x1.z,x1.w};
    half8 vh, vl;
    #pragma unroll
    for (int q=0;q<8;q++){
        float g = (float)(n0+q) * (1.0f/4095.0f);
        float v = xv[q]*w00 + g*w01 + bb;
        _Float16 hi,lo; split_f16(v,hi,lo);
        vh[q]=hi; vl[q]=lo;
    }
    size_t o = ((size_t)(b*128+w))*4096 + n0;
    *reinterpret_cast<half8*>(&hh[o]) = vh;
    *reinterpret_cast<half8*>(&hl[o]) = vl;
}

// ---------------- CFT magnitude (16 groups of 8 channels) ----------------
__global__ void k_cft(const _Float16* __restrict__ hh, const _Float16* __restrict__ hl,
                      const float* __restrict__ Wre, const float* __restrict__ Wim,
                      const float* __restrict__ wl, const float* __restrict__ wr,
                      const int* __restrict__ li, float* __restrict__ magp){
    int b = blockIdx.x, cg = blockIdx.y;
    int f = threadIdx.x;   // 128
    __shared__ float sig[LM];
    __shared__ float swl[LM], swr[LM];
    __shared__ int   sli[LM];
    for (int s=f; s<LM; s+=128){ swl[s]=wl[s]; swr[s]=wr[s]; sli[s]=li[s]; }
    __syncthreads();
    float acc = 0.f;
    for (int cc=0; cc<8; cc++){
        int c = cg*8 + cc;
        const _Float16* rh = hh + ((size_t)(b*128+c))*4096;
        const _Float16* rl = hl + ((size_t)(b*128+c))*4096;
        for (int s=f; s<LM; s+=128){
            int le = sli[s];
            float v0 = (float)rh[le]   + (float)rl[le]*LO_INV;
            float v1 = (float)rh[le+1] + (float)rl[le+1]*LO_INV;
            sig[s] = swl[s]*v0 + swr[s]*v1;
        }
        __syncthreads();
        float re=0.f, im=0.f;
        #pragma unroll 8
        for (int s=0;s<LM;s++){
            float sv = sig[s];
            re = fmaf(sv, Wre[s*128+f], re);
            im = fmaf(sv, Wim[s*128+f], im);
        }
        acc += sqrtf(re*re+im*im);
        __syncthreads();
    }
    magp[(b*16+cg)*128 + f] = acc;
}

__global__ void k_gate(const float* __restrict__ magp, const float* __restrict__ gW,
                       const float* __restrict__ gB, float* __restrict__ gate, int layer){
    int b = blockIdx.x, w = threadIdx.x;
    __shared__ float ms[128];
    float s = 0.f;
    #pragma unroll
    for (int g=0; g<16; g++) s += magp[(b*16+g)*128 + w];
    ms[w] = s * (1.0f/128.0f);
    __syncthreads();
    const float* gwr = gW + ((size_t)layer*128 + w)*128;
    float a = gB[layer*128 + w];
    #pragma unroll 8
    for (int fq=0; fq<128; fq++) a = fmaf(ms[fq], gwr[fq], a);
    gate[b*128+w] = 1.0f/(1.0f+expf(-a));
}

// ---------------- forward DFT: split-K=2, A-only LDS dbuf, B direct packed fragments ----------------
// grid 1024 = 4(col) x 128(row) x 2(ksplit); 4 blocks/CU -> 16 waves/CU.
__global__ __launch_bounds__(256) void k_fdft(
        const _Float16* __restrict__ hh, const _Float16* __restrict__ hl,
        const _Float16* __restrict__ Tffh, const _Float16* __restrict__ Tffl,
        float* __restrict__ Fp){
    __shared__ _Float16 Ah[2][64][40], Al[2][64][40];
    int id = blockIdx.x;
    int swz = (id & 7)*128 + (id >> 3);       // bijective for 1024
    int bx = swz & 3, by = (swz >> 2) & 127, ks = swz >> 9;
    int col0 = bx*64, row0 = by*64, kbase = ks*2048;
    int tid = threadIdx.x, lane = tid & 63, w = tid >> 6;
    int wr = (w>>1)*32, wc = (w&1)*32;
    int l15 = lane & 15, l4 = lane >> 4;
    f32x4 acc[2][2] = {}; f32x4 acc2[2][2] = {};
    int srow = tid >> 2, sseg = tid & 3;
    const _Float16* pa_h = hh + (size_t)(row0+srow)*4096 + kbase + sseg*8;
    const _Float16* pa_l = hl + (size_t)(row0+srow)*4096 + kbase + sseg*8;
    int ct0 = (col0 + wc) >> 4;
    int ckb = ks*64;                          // global chunk base for B fragments
    const _Float16* pfh = Tffh + (size_t)lane*8;
    const _Float16* pfl = Tffl + (size_t)lane*8;
    half8 a0h,a0l,a1h,a1l;
    half8 bf0[4], bf1[4];
#define LOADA(xh,xl,ck) do{ \
    xh = *reinterpret_cast<const half8*>(pa_h + (size_t)(ck)*32); \
    xl = *reinterpret_cast<const half8*>(pa_l + (size_t)(ck)*32); }while(0)
#define WRITEA(xh,xl,buf) do{ \
    *reinterpret_cast<half8*>(&Ah[buf][srow][sseg*8]) = xh; \
    *reinterpret_cast<half8*>(&Al[buf][srow][sseg*8]) = xl; }while(0)
#define LOADB(dst,ck) do{ \
    dst[0] = *reinterpret_cast<const half8*>(pfh + (((size_t)(ct0  )*128 + ckb + (ck))<<9)); \
    dst[1] = *reinterpret_cast<const half8*>(pfh + (((size_t)(ct0+1)*128 + ckb + (ck))<<9)); \
    dst[2] = *reinterpret_cast<const half8*>(pfl + (((size_t)(ct0  )*128 + ckb + (ck))<<9)); \
    dst[3] = *reinterpret_cast<const half8*>(pfl + (((size_t)(ct0+1)*128 + ckb + (ck))<<9)); }while(0)
#define MMF(buf,BF) do{ \
    _Pragma("unroll") for (int i=0;i<2;i++){ \
        half8 fah = *reinterpret_cast<const half8*>(&Ah[buf][wr + i*16 + l15][l4*8]); \
        half8 fal = *reinterpret_cast<const half8*>(&Al[buf][wr + i*16 + l15][l4*8]); \
        _Pragma("unroll") for (int j=0;j<2;j++){ \
            acc[i][j]  = __builtin_amdgcn_mfma_f32_16x16x32_f16(fah, BF[j],   acc[i][j], 0,0,0); \
            acc2[i][j] = __builtin_amdgcn_mfma_f32_16x16x32_f16(fah, BF[2+j], acc2[i][j],0,0,0); \
            acc2[i][j] = __builtin_amdgcn_mfma_f32_16x16x32_f16(fal, BF[j],   acc2[i][j],0,0,0); } } }while(0)
    LOADA(a0h,a0l,0); WRITEA(a0h,a0l,0);
    LOADA(a0h,a0l,1);
    LOADA(a1h,a1l,2);
    LOADB(bf0,0); LOADB(bf1,1);
    __syncthreads();
    for (int tt=0; tt<32; ++tt){
        int t = tt*2;
        MMF(0,bf0);
        WRITEA(a0h,a0l,1);                  // chunk t+1
        if (t+2 < 64) LOADB(bf0, t+2);
        if (t+3 < 64) LOADA(a0h,a0l, t+3);
        __syncthreads();
        MMF(1,bf1);
        if (t+2 < 64) WRITEA(a1h,a1l,0);    // chunk t+2
        if (t+3 < 64) LOADB(bf1, t+3);
        if (t+4 < 64) LOADA(a1h,a1l, t+4);
        __syncthreads();
    }
#undef LOADA
#undef WRITEA
#undef LOADB
#undef MMF
    float* Fo = Fp + (size_t)ks*2097152;
    #pragma unroll
    for (int i=0;i<2;i++)
        #pragma unroll
        for (int j=0;j<2;j++)
            #pragma unroll
            for (int r=0;r<4;r++){
                int row = row0 + wr + i*16 + l4*4 + r;
                int col = col0 + wc + j*16 + l15;
                Fo[(size_t)row*256 + col] = acc[i][j][r] + acc2[i][j][r]*LO_INV;
            }
}

// ---------------- mode mix: sums 2 split-K parts; X = g*(F.wA)+(1-g)*(F.wB) ----------------
__global__ __launch_bounds__(256) void k_modemix(const float* __restrict__ Fp,
        const float* __restrict__ wsum, const float* __restrict__ gate,
        _Float16* __restrict__ Xh, _Float16* __restrict__ Xl, int layer){
    int b = blockIdx.x, og = blockIdx.y;
    __shared__ float Fs[16][256];
    __shared__ float Wa_re[128][8], Wa_im[128][8], Wb_re[128][8], Wb_im[128][8];
    int tid = threadIdx.x;
    for (int e=tid; e<1024; e+=256){
        int i = e>>3, oo = e&7;
        size_t base = ((size_t)layer*128 + i)*128 + og*8 + oo;
        Wa_re[i][oo] = wsum[0*65536 + base];
        Wa_im[i][oo] = wsum[1*65536 + base];
        Wb_re[i][oo] = wsum[2*65536 + base];
        Wb_im[i][oo] = wsum[3*65536 + base];
    }
    int f = tid & 127, half = tid >> 7;
    float pre[4]={},pim[4]={},qre[4]={},qim[4]={};
    for (int i0=0;i0<128;i0+=16){
        for (int e=tid; e<4096; e+=256){
            int ii = e >> 8, k2 = e & 255;
            size_t idx = ((size_t)(b*128 + i0+ii))*256 + k2;
            Fs[ii][k2] = Fp[idx] + Fp[idx + 2097152];
        }
        __syncthreads();
        #pragma unroll
        for (int ii=0; ii<16; ii++){
            float fre = Fs[ii][2*f], fim = Fs[ii][2*f+1];
            int i = i0+ii;
            #pragma unroll
            for (int q=0;q<4;q++){
                int oo = half*4+q;
                float are=Wa_re[i][oo], aim=Wa_im[i][oo];
                float bre=Wb_re[i][oo], bim=Wb_im[i][oo];
                pre[q] = fmaf(fre, are, fmaf(-fim, aim, pre[q]));
                pim[q] = fmaf(fre, aim, fmaf( fim, are, pim[q]));
                qre[q] = fmaf(fre, bre, fmaf(-fim, bim, qre[q]));
                qim[q] = fmaf(fre, bim, fmaf( fim, bre, qim[q]));
            }
        }
        __syncthreads();
    }
    #pragma unroll
    for (int q=0;q<4;q++){
        int o = og*8 + half*4 + q;
        float g = gate[b*128+o];
        float xre = g*pre[q] + (1.f-g)*qre[q];
        float xim = g*pim[q] + (1.f-g)*qim[q];
        float s = (f==0) ? (1.0f/4096.0f) : (2.0f/4096.0f);
        xre *= s; xim *= s;
        if (f==0) xim = 0.f;
        size_t base = ((size_t)(b*128+o))*256 + 2*f;
        _Float16 h1,l1; split_f16(xre,h1,l1); Xh[base]=h1;   Xl[base]=l1;
        _Float16 h2,l2; split_f16(xim,h2,l2); Xh[base+1]=h2; Xl[base+1]=l2;
    }
}

// ---------------- fused in-place layer (R11 proven): 12-chunk pipeline; Ti via packed fragments ----------------
__global__ __launch_bounds__(256) void k_flayer(
    const _Float16* __restrict__ Xh, const _Float16* __restrict__ Xl,
    const _Float16* __restrict__ Tifh, const _Float16* __restrict__ Tifl,
    const _Float16* __restrict__ cWh, const _Float16* __restrict__ cWl,
    const float* __restrict__ convB,
    _Float16* __restrict__ hh, _Float16* __restrict__ hl,
    int layer, int applyGelu){
    __shared__ _Float16 As_h[2][128][40], As_l[2][128][40];   // 40960 B
    __shared__ _Float16 Bs_h[2][64][40],  Bs_l[2][64][40];    // 20480 B (conv only)
    int n0 = blockIdx.x*64;
    int b  = blockIdx.y;
    int tid = threadIdx.x, lane = tid & 63, w = tid >> 6;
    int l15 = lane & 15, l4 = lane >> 4;
    int o0 = w*32;
    int aro = tid >> 2, asl = tid & 3;
    int ctc = tid >> 3, ctn = tid & 7;
    int ocp = ((tid >> 6) ^ (tid & 3));
    const _Float16* cA_h = cWh + (size_t)layer*16384 + (size_t)aro*128 + asl*8;
    const _Float16* cA_l = cWl + (size_t)layer*16384 + (size_t)aro*128 + asl*8;
    const _Float16* xA_h = Xh + ((size_t)(b*128 + aro))*256 + asl*8;
    const _Float16* xA_l = Xl + ((size_t)(b*128 + aro))*256 + asl*8;
    const _Float16* hB_h = hh + ((size_t)(b*128 + ctc))*4096 + n0 + ctn*8;
    const _Float16* hB_l = hl + ((size_t)(b*128 + ctc))*4096 + n0 + ctn*8;
    int nt0 = n0 >> 4;
    const _Float16* pTh = Tifh + (size_t)lane*8;
    const _Float16* pTl = Tifl + (size_t)lane*8;
    f32x4 acc[2][4] = {}; f32x4 acc2[2][4] = {};
    half8 rA[6], rB[6];
    half8 bf0[8], bf1[8];
#define LOADR(r,ck) do{ \
    if ((ck) < 4){ size_t kk = (size_t)(ck)*32; \
        r[0] = *reinterpret_cast<const half8*>(cA_h + kk); \
        r[1] = *reinterpret_cast<const half8*>(cA_l + kk); \
        r[2] = *reinterpret_cast<const half8*>(cA_h + 64*128 + kk); \
        r[3] = *reinterpret_cast<const half8*>(cA_l + 64*128 + kk); \
        r[4] = *reinterpret_cast<const half8*>(hB_h + (size_t)(ck)*32*4096); \
        r[5] = *reinterpret_cast<const half8*>(hB_l + (size_t)(ck)*32*4096); \
    } else { size_t kk = (size_t)((ck)-4)*32; \
        r[0] = *reinterpret_cast<const half8*>(xA_h + kk); \
        r[1] = *reinterpret_cast<const half8*>(xA_l + kk); \
        r[2] = *reinterpret_cast<const half8*>(xA_h + 64*256 + kk); \
        r[3] = *reinterpret_cast<const half8*>(xA_l + 64*256 + kk); } }while(0)
#define WRITER(r,buf,ck) do{ \
    *reinterpret_cast<half8*>(&As_h[buf][aro][asl*8])    = r[0]; \
    *reinterpret_cast<half8*>(&As_l[buf][aro][asl*8])    = r[1]; \
    *reinterpret_cast<half8*>(&As_h[buf][aro+64][asl*8]) = r[2]; \
    *reinterpret_cast<half8*>(&As_l[buf][aro+64][asl*8]) = r[3]; \
    if ((ck) < 4){ \
        _Pragma("unroll") for (int j2=0;j2<8;j2++){ \
            int n1 = ctn*8 + j2; \
            Bs_h[buf][n1][ocp*8 + (ctc&7)] = r[4][j2]; \
            Bs_l[buf][n1][ocp*8 + (ctc&7)] = r[5][j2]; } } }while(0)
#define LOADBF(dst,ckp) do{ \
    _Pragma("unroll") for (int j=0;j<4;j++){ \
        dst[j]   = *reinterpret_cast<const half8*>(pTh + (((size_t)((nt0+j)*8 + (ckp)))<<9)); \
        dst[4+j] = *reinterpret_cast<const half8*>(pTl + (((size_t)((nt0+j)*8 + (ckp)))<<9)); } }while(0)
#define MML(buf,ck,BF) do{ \
    half8 bh[4], bl[4]; \
    if ((ck) < 4){ \
        _Pragma("unroll") for (int j=0;j<4;j++){ \
            int n = j*16 + l15; int sl = (l4 ^ ((n>>3)&3)); \
            bh[j] = *reinterpret_cast<const half8*>(&Bs_h[buf][n][sl*8]); \
            bl[j] = *reinterpret_cast<const half8*>(&Bs_l[buf][n][sl*8]); } \
    } else { \
        _Pragma("unroll") for (int j=0;j<4;j++){ bh[j] = BF[j]; bl[j] = BF[4+j]; } } \
    _Pragma("unroll") for (int i=0;i<2;i++){ \
        half8 ah = *reinterpret_cast<const half8*>(&As_h[buf][o0+i*16+l15][l4*8]); \
        half8 al = *reinterpret_cast<const half8*>(&As_l[buf][o0+i*16+l15][l4*8]); \
        _Pragma("unroll") for (int j=0;j<4;j++){ \
            acc[i][j]  = __builtin_amdgcn_mfma_f32_16x16x32_f16(ah, bh[j], acc[i][j], 0,0,0); \
            acc2[i][j] = __builtin_amdgcn_mfma_f32_16x16x32_f16(ah, bl[j], acc2[i][j],0,0,0); \
            acc2[i][j] = __builtin_amdgcn_mfma_f32_16x16x32_f16(al, bh[j], acc2[i][j],0,0,0); } } }while(0)
    LOADR(rA, 0);
    WRITER(rA, 0, 0);
    LOADR(rA, 1);
    LOADR(rB, 2);
    __syncthreads();
    #pragma unroll
    for (int tt=0; tt<6; ++tt){
        const int t = 2*tt;
        MML(0, t, bf0);
        WRITER(rA, 1, t+1);
        if (t+2 >= 4 && t+2 < 12) LOADBF(bf0, t+2-4);
        if (t+3 < 12) LOADR(rA, t+3);
        __syncthreads();
        MML(1, t+1, bf1);
        if (t+2 < 12) WRITER(rB, 0, t+2);
        if (t+3 >= 4 && t+3 < 12) LOADBF(bf1, t+3-4);
        if (t+4 < 12) LOADR(rB, t+4);
        __syncthreads();
    }
#undef LOADR
#undef WRITER
#undef LOADBF
#undef MML
    // epilogue: bias (+gelu), split, write back in place
    #pragma unroll
    for (int i=0;i<2;i++)
        #pragma unroll
        for (int j=0;j<4;j++)
            #pragma unroll
            for (int r=0;r<4;r++){
                int o = o0 + i*16 + l4*4 + r;
                int n = n0 + j*16 + l15;
                float v = acc[i][j][r] + acc2[i][j][r]*LO_INV + convB[layer*128+o];
                if (applyGelu) v = gelu_f(v);
                _Float16 hi,lo; split_f16(v,hi,lo);
                size_t oi = ((size_t)(b*128+o))*4096 + n;
                hh[oi] = hi; hl[oi] = lo;
            }
}

// ---------------- head (MFMA) ----------------
__global__ __launch_bounds__(256) void k_head(
        const _Float16* __restrict__ hh, const _Float16* __restrict__ hl,
        const _Float16* __restrict__ f1h, const _Float16* __restrict__ f1l,
        const float* __restrict__ fc1b,
        const float* __restrict__ fc2W, const float* __restrict__ fc2b,
        float* __restrict__ out){
    __shared__ _Float16 Bch[64][136], Bcl[64][136];
    __shared__ _Float16 Ash[128][40], Asl[128][40];
    __shared__ float red[16][64];
    int n0 = blockIdx.x*64;
    int b  = blockIdx.y;
    int tid = threadIdx.x, lane = tid & 63, w = tid >> 6;
    int l15 = lane & 15, l4 = lane >> 4;
    int j0 = w*32;
    {
        int c = tid & 127, nh = tid >> 7;
        const _Float16* rh = hh + ((size_t)(b*128+c))*4096 + n0 + nh*32;
        const _Float16* rl = hl + ((size_t)(b*128+c))*4096 + n0 + nh*32;
        #pragma unroll
        for (int j=0;j<4;j++){
            half8 vhv = *reinterpret_cast<const half8*>(rh + j*8);
            half8 vlv = *reinterpret_cast<const half8*>(rl + j*8);
            #pragma unroll
            for (int q=0;q<8;q++){
                int n = nh*32 + j*8 + q;
                Bch[n][c] = vhv[q];
                Bcl[n][c] = vlv[q];
            }
        }
    }
    __syncthreads();
    int so2 = tid >> 2, sseg = tid & 3;
    f32x4 acc[2][4] = {}; f32x4 acc2[2][4] = {};
    for (int k0=0;k0<128;k0+=32){
        #pragma unroll
        for (int p=0;p<2;p++){
            int o = p*64 + so2;
            *reinterpret_cast<half8*>(&Ash[o][sseg*8]) =
                *reinterpret_cast<const half8*>(&f1h[(size_t)o*128 + k0 + sseg*8]);
            *reinterpret_cast<half8*>(&Asl[o][sseg*8]) =
                *reinterpret_cast<const half8*>(&f1l[(size_t)o*128 + k0 + sseg*8]);
        }
        __syncthreads();
        half8 ah[2],al[2],bh[4],bl[4];
        #pragma unroll
        for (int i=0;i<2;i++){
            ah[i] = *reinterpret_cast<const half8*>(&Ash[j0+i*16+l15][l4*8]);
            al[i] = *reinterpret_cast<const half8*>(&Asl[j0+i*16+l15][l4*8]);
        }
        #pragma unroll
        for (int j=0;j<4;j++){
            bh[j] = *reinterpret_cast<const half8*>(&Bch[j*16+l15][k0+l4*8]);
            bl[j] = *reinterpret_cast<const half8*>(&Bcl[j*16+l15][k0+l4*8]);
        }
        #pragma unroll
        for (int i=0;i<2;i++)
            #pragma unroll
            for (int j=0;j<4;j++){
                acc[i][j]  = __builtin_amdgcn_mfma_f32_16x16x32_f16(ah[i], bh[j], acc[i][j], 0,0,0);
                acc2[i][j] = __builtin_amdgcn_mfma_f32_16x16x32_f16(ah[i], bl[j], acc2[i][j],0,0,0);
                acc2[i][j] = __builtin_amdgcn_mfma_f32_16x16x32_f16(al[i], bh[j], acc2[i][j],0,0,0);
            }
        __syncthreads();
    }
    float part[4];
    #pragma unroll
    for (int j=0;j<4;j++) part[j] = 0.f;
    #pragma unroll
    for (int i=0;i<2;i++){
        #pragma unroll
        for (int r=0;r<4;r++){
            int jj = j0 + i*16 + l4*4 + r;
            float b1 = fc1b[jj];
            float w2 = fc2W[jj];
            #pragma unroll
            for (int j=0;j<4;j++){
                float v = acc[i][j][r] + acc2[i][j][r]*LO_INV + b1;
                part[j] = fmaf(w2, gelu_f(v), part[j]);
            }
        }
    }
    #pragma unroll
    for (int j=0;j<4;j++) red[w*4+l4][j*16+l15] = part[j];
    __syncthreads();
    if (tid < 64){
        float s = fc2b[0];
        #pragma unroll
        for (int r=0;r<16;r++) s += red[r][tid];
        out[((size_t)b<<12) + n0 + tid] = s;
    }
}

extern "C" void kernel_launch(void* const* d_in, const int* in_sizes, int n_in,
                              void* d_out, int out_size, void* d_ws, size_t ws_size,
                              hipStream_t stream) {
    const float* x     = (const float*)d_in[0];
    const float* fc0W  = (const float*)d_in[1];
    const float* fc0b  = (const float*)d_in[2];
    const float* gateW = (const float*)d_in[3];
    const float* gateB = (const float*)d_in[4];
    const float* wAre  = (const float*)d_in[5];
    const float* wAim  = (const float*)d_in[6];
    const float* wBre  = (const float*)d_in[7];
    const float* wBim  = (const float*)d_in[8];
    const float* convW = (const float*)d_in[9];
    const float* convB = (const float*)d_in[10];
    const float* fc1W  = (const float*)d_in[11];
    const float* fc1b  = (const float*)d_in[12];
    const float* fc2W  = (const float*)d_in[13];
    const float* fc2b  = (const float*)d_in[14];
    float* out = (float*)d_out;
    char*  wsb = (char*)d_ws;

    float* Fp   = (float*)(wsb + BY_F);
    float* wsum = (float*)(wsb + BY_wsum);
    float* Wcre = (float*)(wsb + BY_Wcre);
    float* Wcim = (float*)(wsb + BY_Wcim);
    float* wl   = (float*)(wsb + BY_wl);
    float* wr   = (float*)(wsb + BY_wr);
    int*   li   = (int*)(wsb + BY_li);
    float* magp = (float*)(wsb + BY_magp);
    float* gate = (float*)(wsb + BY_gate);
    _Float16* hh   = (_Float16*)(wsb + BY_hh);
    _Float16* hl   = (_Float16*)(wsb + BY_hl);
    _Float16* Tffh = (_Float16*)(wsb + BY_Tfh);
    _Float16* Tffl = (_Float16*)(wsb + BY_Tfl);
    _Float16* Tifh = (_Float16*)(wsb + BY_Tih);
    _Float16* Tifl = (_Float16*)(wsb + BY_Til);
    _Float16* Xh   = (_Float16*)(wsb + BY_Xh);
    _Float16* Xl   = (_Float16*)(wsb + BY_Xl);
    _Float16* cWh  = (_Float16*)(wsb + BY_cWh);
    _Float16* cWl  = (_Float16*)(wsb + BY_cWl);
    _Float16* f1h  = (_Float16*)(wsb + BY_f1h);
    _Float16* f1l  = (_Float16*)(wsb + BY_f1l);

    k_tables<<<4096, 256, 0, stream>>>(Tffh, Tffl, Tifh, Tifl);
    k_cft_tables<<<160, 128, 0, stream>>>(Wcre, Wcim, wl, wr, li);
    k_wsum<<<dim3(16384,4), 256, 0, stream>>>(wAre, wAim, wBre, wBim, wsum);
    k_wsplit<<<320, 256, 0, stream>>>(convW, fc1W, cWh, cWl, f1h, f1l);
    k_h0<<<16384, 256, 0, stream>>>(x, fc0W, fc0b, hh, hl);

    for (int layer=0; layer<4; layer++){
        k_cft<<<dim3(64,16), 128, 0, stream>>>(hh, hl, Wcre, Wcim, wl, wr, li, magp);
        k_gate<<<64, 128, 0, stream>>>(magp, gateW, gateB, gate, layer);
        k_fdft<<<1024, 256, 0, stream>>>(hh, hl, Tffh, Tffl, Fp);
        k_modemix<<<dim3(64,16), 256, 0, stream>>>(Fp, wsum, gate, Xh, Xl, layer);
        k_flayer<<<dim3(64,64), 256, 0, stream>>>(Xh, Xl, Tifh, Tifl, cWh, cWl, convB,
                                                  hh, hl, layer, layer<3 ? 1:0);
    }
    k_head<<<dim3(64,64), 256, 0, stream>>>(hh, hl, f1h, f1l, fc1b, fc2W, fc2b, out);
    (void)in_sizes; (void)n_in; (void)out_size; (void)ws_size;
}

// Round 15
// 1338.479 us; speedup vs baseline: 1.0838x; 1.0268x over previous
//
#include <hip/hip_runtime.h>
#include <math.h>

#define B_SZ 64
#define WID 128
#define NPT 4096
#define MODES 128
#define LSEG 20
#define MCH 8
#define LM 160   // LSEG*MCH

typedef _Float16 half8 __attribute__((ext_vector_type(8)));
typedef float f32x4 __attribute__((ext_vector_type(4)));

#define LO_SCALE 2048.0f
#define LO_INV   (1.0f/2048.0f)

// ---------------- workspace layout (bytes), total ~170 MB ----------------
static constexpr size_t BY_F    = 0;                       // fp32 [2 ksplit][8192][256]
static constexpr size_t BY_wsum = BY_F + 16777216;         // fp32 [4][4][128][128]
static constexpr size_t BY_Wcre = BY_wsum + 1048576;       // fp32 [160][128]
static constexpr size_t BY_Wcim = BY_Wcre + 81920;
static constexpr size_t BY_wl   = BY_Wcim + 81920;         // fp32 [160] (pad)
static constexpr size_t BY_wr   = BY_wl + 1024;
static constexpr size_t BY_li   = BY_wr + 1024;            // int [160]
static constexpr size_t BY_magp = BY_li + 1024;            // fp32 [64][16][128]
static constexpr size_t BY_gate = BY_magp + 524288;        // fp32 [64][128]
static constexpr size_t BY_hh   = BY_gate + 32768;         // f16 [64][128][4096] split-hi
static constexpr size_t BY_hl   = BY_hh + 67108864;        // f16 split-lo
static constexpr size_t BY_Tfh  = BY_hl + 67108864;        // f16 frag-packed fwd [16][128][64][8]
static constexpr size_t BY_Tfl  = BY_Tfh + 2097152;
static constexpr size_t BY_Tih  = BY_Tfl + 2097152;        // f16 frag-packed inv [256][8][64][8]
static constexpr size_t BY_Til  = BY_Tih + 2097152;
static constexpr size_t BY_Xh   = BY_Til + 2097152;        // f16 [64][128][256]
static constexpr size_t BY_Xl   = BY_Xh + 4194304;
static constexpr size_t BY_cWh  = BY_Xl + 4194304;         // f16 [4][128][128]
static constexpr size_t BY_cWl  = BY_cWh + 131072;
static constexpr size_t BY_f1h  = BY_cWl + 131072;         // f16 [128][128]
static constexpr size_t BY_f1l  = BY_f1h + 32768;
static constexpr size_t BY_end  = BY_f1l + 32768;

__device__ __forceinline__ float gelu_f(float x){
    return 0.5f*x*(1.0f+erff(x*0.70710678118654752f));
}
__device__ __forceinline__ void split_f16(float v, _Float16& hi, _Float16& lo){
    hi = (_Float16)v;
    lo = (_Float16)((v - (float)hi)*LO_SCALE);
}

// ---------------- tables (split f16, MFMA-fragment-packed) ----------------
__global__ void k_tables(_Float16* __restrict__ Tffh, _Float16* __restrict__ Tffl,
                         _Float16* __restrict__ Tifh, _Float16* __restrict__ Tifl){
    int idx = blockIdx.x*256 + threadIdx.x;   // 4096*256
    int n = idx >> 8, k2 = idx & 255;
    int f = k2 >> 1;
    int m = (n*f) & 4095;
    double th = (double)m * (3.14159265358979323846/2048.0);
    double s, c; sincos(th, &s, &c);
    float vf = (k2&1) ? (float)(-s) : (float)c;
    {
        _Float16 h1,l1; split_f16(vf, h1, l1);
        int ct = k2>>4, ck = n>>5;
        int lane = (((n>>3)&3)<<4) | (k2&15);
        int j = n & 7;
        size_t off = (((size_t)(ct*128 + ck))<<9) + lane*8 + j;
        Tffh[off] = h1; Tffl[off] = l1;
    }
    float vi;
    if (k2 == 0)      vi = 1.0f;
    else if (k2 == 1) vi = 0.0f;
    else              vi = vf;
    {
        _Float16 h2,l2; split_f16(vi, h2, l2);
        int nt = n>>4, ck2 = k2>>5;
        int lane = (((k2>>3)&3)<<4) | (n&15);
        int j = k2 & 7;
        size_t off = (((size_t)(nt*8 + ck2))<<9) + lane*8 + j;
        Tifh[off] = h2; Tifl[off] = l2;
    }
}

__global__ void k_cft_tables(float* __restrict__ Wre, float* __restrict__ Wim,
                             float* __restrict__ wl, float* __restrict__ wr,
                             int* __restrict__ li){
    int idx = blockIdx.x*128 + threadIdx.x;   // 160*128
    if (idx >= LM*MODES) return;
    int lm = idx >> 7;  int f = idx & 127;
    int l = lm / MCH, m = lm % MCH;
    const double PI = 3.14159265358979323846;
    double nodes[8], Tm[8];
    #pragma unroll
    for (int j=0;j<8;j++){
        nodes[j] = -cos((2.0*j+1.0)*PI/16.0);
        Tm[j] = cos((double)m * acos(nodes[j]));
    }
    double wp = (double)f * PI * 0.05;
    double cwre=0.0, cwim=0.0;
    #pragma unroll
    for (int j=0;j<8;j++){
        double sj, cj; sincos(nodes[j]*wp, &sj, &cj);
        cwre += Tm[j]*cj;
        cwim -= Tm[j]*sj;
    }
    cwre *= 0.025; cwim *= 0.025;
    int r = (f*l) % 20;
    double sa = 2.0*PI*(double)r/20.0;
    double shre = cos(sa), shim = -sin(sa);
    Wre[lm*128+f] = (float)(shre*cwre - shim*cwim);
    Wim[lm*128+f] = (float)(shre*cwim + shim*cwre);
    if (f == 0){
        double v = (double)l/20.0 + 0.025*(nodes[m]+1.0);
        int rr = (int)ceil(v*4095.0);
        if (rr > 4095) rr = 4095;
        if (rr < 1) rr = 1;
        int le = rr-1;
        double tl = (double)le/4095.0, tr = (double)rr/4095.0;
        double wrv = (v - tl)/(tr - tl);
        li[lm] = le;
        wl[lm] = (float)(1.0 - wrv);
        wr[lm] = (float)wrv;
    }
}

// sum wA/wB over mode axis
__global__ void k_wsum(const float* __restrict__ wAre, const float* __restrict__ wAim,
                       const float* __restrict__ wBre, const float* __restrict__ wBim,
                       float* __restrict__ out){
    int row  = blockIdx.x*4 + (threadIdx.x>>6);
    int lane = threadIdx.x & 63;
    const float* src = (blockIdx.y==0)?wAre:(blockIdx.y==1)?wAim:(blockIdx.y==2)?wBre:wBim;
    float v = src[(size_t)row*128 + lane] + src[(size_t)row*128 + 64 + lane];
    #pragma unroll
    for (int o=32;o>0;o>>=1) v += __shfl_down(v, o);
    if (lane==0) out[(size_t)blockIdx.y*65536 + row] = v;
}

// pre-split conv & fc1 weights (linear layouts)
__global__ void k_wsplit(const float* __restrict__ convW, const float* __restrict__ fc1W,
                         _Float16* __restrict__ cWh, _Float16* __restrict__ cWl,
                         _Float16* __restrict__ f1h, _Float16* __restrict__ f1l){
    int idx = blockIdx.x*256 + threadIdx.x;   // 81920
    if (idx < 65536){
        _Float16 hi,lo; split_f16(convW[idx], hi, lo);
        cWh[idx]=hi; cWl[idx]=lo;
    } else {
        int j = idx - 65536;
        _Float16 hi,lo; split_f16(fc1W[j], hi, lo);
        f1h[j]=hi; f1l[j]=lo;
    }
}

// ---------------- lift: write split h ----------------
__global__ void k_h0(const float* __restrict__ x, const float* __restrict__ w0,
                     const float* __restrict__ b0,
                     _Float16* __restrict__ hh, _Float16* __restrict__ hl){
    int idx = blockIdx.x*256 + threadIdx.x;  // 64*128*512
    int n8 = idx & 511;
    int w  = (idx >> 9) & 127;
    int b  = idx >> 16;
    int n0 = n8*8;
    float w00 = w0[w*2], w01 = w0[w*2+1], bb = b0[w];
    const float* xr = &x[((size_t)b<<12) + n0];
    float4 x0 = *reinterpret_cast<const float4*>(xr);
    float4 x1 = *reinterpret_cast<const float4*>(xr+4);
    float xv[8]={x0.x,x0.y,x0.z,x0.w,x1.x,x1.y,x1.z,x1.w};
    half8 vh, vl;
    #pragma unroll
    for (int q=0;q<8;q++){
        float g = (float)(n0+q) * (1.0f/4095.0f);
        float v = xv[q]*w00 + g*w01 + bb;
        _Float16 hi,lo; split_f16(v,hi,lo);
        vh[q]=hi; vl[q]=lo;
    }
    size_t o = ((size_t)(b*128+w))*4096 + n0;
    *reinterpret_cast<half8*>(&hh[o]) = vh;
    *reinterpret_cast<half8*>(&hl[o]) = vl;
}

// ---------------- CFT magnitude (16 groups of 8 channels) ----------------
__global__ void k_cft(const _Float16* __restrict__ hh, const _Float16* __restrict__ hl,
                      const float* __restrict__ Wre, const float* __restrict__ Wim,
                      const float* __restrict__ wl, const float* __restrict__ wr,
                      const int* __restrict__ li, float* __restrict__ magp){
    int b = blockIdx.x, cg = blockIdx.y;
    int f = threadIdx.x;   // 128
    __shared__ float sig[LM];
    __shared__ float swl[LM], swr[LM];
    __shared__ int   sli[LM];
    for (int s=f; s<LM; s+=128){ swl[s]=wl[s]; swr[s]=wr[s]; sli[s]=li[s]; }
    __syncthreads();
    float acc = 0.f;
    for (int cc=0; cc<8; cc++){
        int c = cg*8 + cc;
        const _Float16* rh = hh + ((size_t)(b*128+c))*4096;
        const _Float16* rl = hl + ((size_t)(b*128+c))*4096;
        for (int s=f; s<LM; s+=128){
            int le = sli[s];
            float v0 = (float)rh[le]   + (float)rl[le]*LO_INV;
            float v1 = (float)rh[le+1] + (float)rl[le+1]*LO_INV;
            sig[s] = swl[s]*v0 + swr[s]*v1;
        }
        __syncthreads();
        float re=0.f, im=0.f;
        #pragma unroll 8
        for (int s=0;s<LM;s++){
            float sv = sig[s];
            re = fmaf(sv, Wre[s*128+f], re);
            im = fmaf(sv, Wim[s*128+f], im);
        }
        acc += sqrtf(re*re+im*im);
        __syncthreads();
    }
    magp[(b*16+cg)*128 + f] = acc;
}

__global__ void k_gate(const float* __restrict__ magp, const float* __restrict__ gW,
                       const float* __restrict__ gB, float* __restrict__ gate, int layer){
    int b = blockIdx.x, w = threadIdx.x;
    __shared__ float ms[128];
    float s = 0.f;
    #pragma unroll
    for (int g=0; g<16; g++) s += magp[(b*16+g)*128 + w];
    ms[w] = s * (1.0f/128.0f);
    __syncthreads();
    const float* gwr = gW + ((size_t)layer*128 + w)*128;
    float a = gB[layer*128 + w];
    #pragma unroll 8
    for (int fq=0; fq<128; fq++) a = fmaf(ms[fq], gwr[fq], a);
    gate[b*128+w] = 1.0f/(1.0f+expf(-a));
}

// ---------------- forward DFT: 64x128 block, split-K=2, A-LDS dbuf, B direct fragments ----------------
// grid 512 = 128(rg) x 2(cg) x 2(ks); 2 blocks/CU; wave tile 32x64 (acc[2][4]).
__global__ __launch_bounds__(256) void k_fdft(
        const _Float16* __restrict__ hh, const _Float16* __restrict__ hl,
        const _Float16* __restrict__ Tffh, const _Float16* __restrict__ Tffl,
        float* __restrict__ Fp){
    __shared__ _Float16 Ah[2][64][40], Al[2][64][40];
    int id = blockIdx.x;
    int swz = (id & 7)*64 + (id >> 3);        // bijective for 512
    int rg = swz & 127, cg = (swz >> 7) & 1, ks = swz >> 8;
    int row0 = rg*64, col0 = cg*128, kbase = ks*2048;
    int tid = threadIdx.x, lane = tid & 63, w = tid >> 6;
    int wr = (w>>1)*32, wc = (w&1)*64;
    int l15 = lane & 15, l4 = lane >> 4;
    f32x4 acc[2][4] = {}; f32x4 acc2[2][4] = {};
    int srow = tid >> 2, sseg = tid & 3;
    const _Float16* pa_h = hh + (size_t)(row0+srow)*4096 + kbase + sseg*8;
    const _Float16* pa_l = hl + (size_t)(row0+srow)*4096 + kbase + sseg*8;
    int ct0 = (col0 + wc) >> 4;
    int ckb = ks*64;                          // chunk base for B fragments
    const _Float16* pfh = Tffh + (size_t)lane*8;
    const _Float16* pfl = Tffl + (size_t)lane*8;
    half8 a0h,a0l,a1h,a1l;
    half8 bf0[8], bf1[8];
#define LOADA(xh,xl,ck) do{ \
    xh = *reinterpret_cast<const half8*>(pa_h + (size_t)(ck)*32); \
    xl = *reinterpret_cast<const half8*>(pa_l + (size_t)(ck)*32); }while(0)
#define WRITEA(xh,xl,buf) do{ \
    *reinterpret_cast<half8*>(&Ah[buf][srow][sseg*8]) = xh; \
    *reinterpret_cast<half8*>(&Al[buf][srow][sseg*8]) = xl; }while(0)
#define LOADB(dst,ck) do{ \
    _Pragma("unroll") for (int j=0;j<4;j++){ \
        dst[j]   = *reinterpret_cast<const half8*>(pfh + (((size_t)(ct0+j)*128 + ckb + (ck))<<9)); \
        dst[4+j] = *reinterpret_cast<const half8*>(pfl + (((size_t)(ct0+j)*128 + ckb + (ck))<<9)); } }while(0)
#define MMF(buf,BF) do{ \
    _Pragma("unroll") for (int i=0;i<2;i++){ \
        half8 fah = *reinterpret_cast<const half8*>(&Ah[buf][wr + i*16 + l15][l4*8]); \
        half8 fal = *reinterpret_cast<const half8*>(&Al[buf][wr + i*16 + l15][l4*8]); \
        _Pragma("unroll") for (int j=0;j<4;j++){ \
            acc[i][j]  = __builtin_amdgcn_mfma_f32_16x16x32_f16(fah, BF[j],   acc[i][j], 0,0,0); \
            acc2[i][j] = __builtin_amdgcn_mfma_f32_16x16x32_f16(fah, BF[4+j], acc2[i][j],0,0,0); \
            acc2[i][j] = __builtin_amdgcn_mfma_f32_16x16x32_f16(fal, BF[j],   acc2[i][j],0,0,0); } } }while(0)
    LOADA(a0h,a0l,0); WRITEA(a0h,a0l,0);
    LOADA(a0h,a0l,1);
    LOADA(a1h,a1l,2);
    LOADB(bf0,0); LOADB(bf1,1);
    __syncthreads();
    for (int tt=0; tt<32; ++tt){
        int t = tt*2;
        MMF(0,bf0);
        WRITEA(a0h,a0l,1);                  // chunk t+1
        if (t+2 < 64) LOADB(bf0, t+2);
        if (t+3 < 64) LOADA(a0h,a0l, t+3);
        __syncthreads();
        MMF(1,bf1);
        if (t+2 < 64) WRITEA(a1h,a1l,0);    // chunk t+2
        if (t+3 < 64) LOADB(bf1, t+3);
        if (t+4 < 64) LOADA(a1h,a1l, t+4);
        __syncthreads();
    }
#undef LOADA
#undef WRITEA
#undef LOADB
#undef MMF
    float* Fo = Fp + (size_t)ks*2097152;
    #pragma unroll
    for (int i=0;i<2;i++)
        #pragma unroll
        for (int j=0;j<4;j++)
            #pragma unroll
            for (int r=0;r<4;r++){
                int row = row0 + wr + i*16 + l4*4 + r;
                int col = col0 + wc + j*16 + l15;
                Fo[(size_t)row*256 + col] = acc[i][j][r] + acc2[i][j][r]*LO_INV;
            }
}

// ---------------- mode mix: sums 2 split-K parts; X = g*(F.wA)+(1-g)*(F.wB) ----------------
__global__ __launch_bounds__(256) void k_modemix(const float* __restrict__ Fp,
        const float* __restrict__ wsum, const float* __restrict__ gate,
        _Float16* __restrict__ Xh, _Float16* __restrict__ Xl, int layer){
    int b = blockIdx.x, og = blockIdx.y;
    __shared__ float Fs[16][256];
    __shared__ float Wa_re[128][8], Wa_im[128][8], Wb_re[128][8], Wb_im[128][8];
    int tid = threadIdx.x;
    for (int e=tid; e<1024; e+=256){
        int i = e>>3, oo = e&7;
        size_t base = ((size_t)layer*128 + i)*128 + og*8 + oo;
        Wa_re[i][oo] = wsum[0*65536 + base];
        Wa_im[i][oo] = wsum[1*65536 + base];
        Wb_re[i][oo] = wsum[2*65536 + base];
        Wb_im[i][oo] = wsum[3*65536 + base];
    }
    int f = tid & 127, half = tid >> 7;
    float pre[4]={},pim[4]={},qre[4]={},qim[4]={};
    for (int i0=0;i0<128;i0+=16){
        for (int e=tid; e<4096; e+=256){
            int ii = e >> 8, k2 = e & 255;
            size_t idx = ((size_t)(b*128 + i0+ii))*256 + k2;
            Fs[ii][k2] = Fp[idx] + Fp[idx + 2097152];
        }
        __syncthreads();
        #pragma unroll
        for (int ii=0; ii<16; ii++){
            float fre = Fs[ii][2*f], fim = Fs[ii][2*f+1];
            int i = i0+ii;
            #pragma unroll
            for (int q=0;q<4;q++){
                int oo = half*4+q;
                float are=Wa_re[i][oo], aim=Wa_im[i][oo];
                float bre=Wb_re[i][oo], bim=Wb_im[i][oo];
                pre[q] = fmaf(fre, are, fmaf(-fim, aim, pre[q]));
                pim[q] = fmaf(fre, aim, fmaf( fim, are, pim[q]));
                qre[q] = fmaf(fre, bre, fmaf(-fim, bim, qre[q]));
                qim[q] = fmaf(fre, bim, fmaf( fim, bre, qim[q]));
            }
        }
        __syncthreads();
    }
    #pragma unroll
    for (int q=0;q<4;q++){
        int o = og*8 + half*4 + q;
        float g = gate[b*128+o];
        float xre = g*pre[q] + (1.f-g)*qre[q];
        float xim = g*pim[q] + (1.f-g)*qim[q];
        float s = (f==0) ? (1.0f/4096.0f) : (2.0f/4096.0f);
        xre *= s; xim *= s;
        if (f==0) xim = 0.f;
        size_t base = ((size_t)(b*128+o))*256 + 2*f;
        _Float16 h1,l1; split_f16(xre,h1,l1); Xh[base]=h1;   Xl[base]=l1;
        _Float16 h2,l2; split_f16(xim,h2,l2); Xh[base+1]=h2; Xl[base+1]=l2;
    }
}

// ---------------- fused in-place layer (R11 proven): 12-chunk pipeline; Ti via packed fragments ----------------
__global__ __launch_bounds__(256) void k_flayer(
    const _Float16* __restrict__ Xh, const _Float16* __restrict__ Xl,
    const _Float16* __restrict__ Tifh, const _Float16* __restrict__ Tifl,
    const _Float16* __restrict__ cWh, const _Float16* __restrict__ cWl,
    const float* __restrict__ convB,
    _Float16* __restrict__ hh, _Float16* __restrict__ hl,
    int layer, int applyGelu){
    __shared__ _Float16 As_h[2][128][40], As_l[2][128][40];   // 40960 B
    __shared__ _Float16 Bs_h[2][64][40],  Bs_l[2][64][40];    // 20480 B (conv only)
    int n0 = blockIdx.x*64;
    int b  = blockIdx.y;
    int tid = threadIdx.x, lane = tid & 63, w = tid >> 6;
    int l15 = lane & 15, l4 = lane >> 4;
    int o0 = w*32;
    int aro = tid >> 2, asl = tid & 3;
    int ctc = tid >> 3, ctn = tid & 7;
    int ocp = ((tid >> 6) ^ (tid & 3));
    const _Float16* cA_h = cWh + (size_t)layer*16384 + (size_t)aro*128 + asl*8;
    const _Float16* cA_l = cWl + (size_t)layer*16384 + (size_t)aro*128 + asl*8;
    const _Float16* xA_h = Xh + ((size_t)(b*128 + aro))*256 + asl*8;
    const _Float16* xA_l = Xl + ((size_t)(b*128 + aro))*256 + asl*8;
    const _Float16* hB_h = hh + ((size_t)(b*128 + ctc))*4096 + n0 + ctn*8;
    const _Float16* hB_l = hl + ((size_t)(b*128 + ctc))*4096 + n0 + ctn*8;
    int nt0 = n0 >> 4;
    const _Float16* pTh = Tifh + (size_t)lane*8;
    const _Float16* pTl = Tifl + (size_t)lane*8;
    f32x4 acc[2][4] = {}; f32x4 acc2[2][4] = {};
    half8 rA[6], rB[6];
    half8 bf0[8], bf1[8];
#define LOADR(r,ck) do{ \
    if ((ck) < 4){ size_t kk = (size_t)(ck)*32; \
        r[0] = *reinterpret_cast<const half8*>(cA_h + kk); \
        r[1] = *reinterpret_cast<const half8*>(cA_l + kk); \
        r[2] = *reinterpret_cast<const half8*>(cA_h + 64*128 + kk); \
        r[3] = *reinterpret_cast<const half8*>(cA_l + 64*128 + kk); \
        r[4] = *reinterpret_cast<const half8*>(hB_h + (size_t)(ck)*32*4096); \
        r[5] = *reinterpret_cast<const half8*>(hB_l + (size_t)(ck)*32*4096); \
    } else { size_t kk = (size_t)((ck)-4)*32; \
        r[0] = *reinterpret_cast<const half8*>(xA_h + kk); \
        r[1] = *reinterpret_cast<const half8*>(xA_l + kk); \
        r[2] = *reinterpret_cast<const half8*>(xA_h + 64*256 + kk); \
        r[3] = *reinterpret_cast<const half8*>(xA_l + 64*256 + kk); } }while(0)
#define WRITER(r,buf,ck) do{ \
    *reinterpret_cast<half8*>(&As_h[buf][aro][asl*8])    = r[0]; \
    *reinterpret_cast<half8*>(&As_l[buf][aro][asl*8])    = r[1]; \
    *reinterpret_cast<half8*>(&As_h[buf][aro+64][asl*8]) = r[2]; \
    *reinterpret_cast<half8*>(&As_l[buf][aro+64][asl*8]) = r[3]; \
    if ((ck) < 4){ \
        _Pragma("unroll") for (int j2=0;j2<8;j2++){ \
            int n1 = ctn*8 + j2; \
            Bs_h[buf][n1][ocp*8 + (ctc&7)] = r[4][j2]; \
            Bs_l[buf][n1][ocp*8 + (ctc&7)] = r[5][j2]; } } }while(0)
#define LOADBF(dst,ckp) do{ \
    _Pragma("unroll") for (int j=0;j<4;j++){ \
        dst[j]   = *reinterpret_cast<const half8*>(pTh + (((size_t)((nt0+j)*8 + (ckp)))<<9)); \
        dst[4+j] = *reinterpret_cast<const half8*>(pTl + (((size_t)((nt0+j)*8 + (ckp)))<<9)); } }while(0)
#define MML(buf,ck,BF) do{ \
    half8 bh[4], bl[4]; \
    if ((ck) < 4){ \
        _Pragma("unroll") for (int j=0;j<4;j++){ \
            int n = j*16 + l15; int sl = (l4 ^ ((n>>3)&3)); \
            bh[j] = *reinterpret_cast<const half8*>(&Bs_h[buf][n][sl*8]); \
            bl[j] = *reinterpret_cast<const half8*>(&Bs_l[buf][n][sl*8]); } \
    } else { \
        _Pragma("unroll") for (int j=0;j<4;j++){ bh[j] = BF[j]; bl[j] = BF[4+j]; } } \
    _Pragma("unroll") for (int i=0;i<2;i++){ \
        half8 ah = *reinterpret_cast<const half8*>(&As_h[buf][o0+i*16+l15][l4*8]); \
        half8 al = *reinterpret_cast<const half8*>(&As_l[buf][o0+i*16+l15][l4*8]); \
        _Pragma("unroll") for (int j=0;j<4;j++){ \
            acc[i][j]  = __builtin_amdgcn_mfma_f32_16x16x32_f16(ah, bh[j], acc[i][j], 0,0,0); \
            acc2[i][j] = __builtin_amdgcn_mfma_f32_16x16x32_f16(ah, bl[j], acc2[i][j],0,0,0); \
            acc2[i][j] = __builtin_amdgcn_mfma_f32_16x16x32_f16(al, bh[j], acc2[i][j],0,0,0); } } }while(0)
    LOADR(rA, 0);
    WRITER(rA, 0, 0);
    LOADR(rA, 1);
    LOADR(rB, 2);
    __syncthreads();
    #pragma unroll
    for (int tt=0; tt<6; ++tt){
        const int t = 2*tt;
        MML(0, t, bf0);
        WRITER(rA, 1, t+1);
        if (t+2 >= 4 && t+2 < 12) LOADBF(bf0, t+2-4);
        if (t+3 < 12) LOADR(rA, t+3);
        __syncthreads();
        MML(1, t+1, bf1);
        if (t+2 < 12) WRITER(rB, 0, t+2);
        if (t+3 >= 4 && t+3 < 12) LOADBF(bf1, t+3-4);
        if (t+4 < 12) LOADR(rB, t+4);
        __syncthreads();
    }
#undef LOADR
#undef WRITER
#undef LOADBF
#undef MML
    // epilogue: bias (+gelu), split, write back in place
    #pragma unroll
    for (int i=0;i<2;i++)
        #pragma unroll
        for (int j=0;j<4;j++)
            #pragma unroll
            for (int r=0;r<4;r++){
                int o = o0 + i*16 + l4*4 + r;
                int n = n0 + j*16 + l15;
                float v = acc[i][j][r] + acc2[i][j][r]*LO_INV + convB[layer*128+o];
                if (applyGelu) v = gelu_f(v);
                _Float16 hi,lo; split_f16(v,hi,lo);
                size_t oi = ((size_t)(b*128+o))*4096 + n;
                hh[oi] = hi; hl[oi] = lo;
            }
}

// ---------------- head (MFMA) ----------------
__global__ __launch_bounds__(256) void k_head(
        const _Float16* __restrict__ hh, const _Float16* __restrict__ hl,
        const _Float16* __restrict__ f1h, const _Float16* __restrict__ f1l,
        const float* __restrict__ fc1b,
        const float* __restrict__ fc2W, const float* __restrict__ fc2b,
        float* __restrict__ out){
    __shared__ _Float16 Bch[64][136], Bcl[64][136];
    __shared__ _Float16 Ash[128][40], Asl[128][40];
    __shared__ float red[16][64];
    int n0 = blockIdx.x*64;
    int b  = blockIdx.y;
    int tid = threadIdx.x, lane = tid & 63, w = tid >> 6;
    int l15 = lane & 15, l4 = lane >> 4;
    int j0 = w*32;
    {
        int c = tid & 127, nh = tid >> 7;
        const _Float16* rh = hh + ((size_t)(b*128+c))*4096 + n0 + nh*32;
        const _Float16* rl = hl + ((size_t)(b*128+c))*4096 + n0 + nh*32;
        #pragma unroll
        for (int j=0;j<4;j++){
            half8 vhv = *reinterpret_cast<const half8*>(rh + j*8);
            half8 vlv = *reinterpret_cast<const half8*>(rl + j*8);
            #pragma unroll
            for (int q=0;q<8;q++){
                int n = nh*32 + j*8 + q;
                Bch[n][c] = vhv[q];
                Bcl[n][c] = vlv[q];
            }
        }
    }
    __syncthreads();
    int so2 = tid >> 2, sseg = tid & 3;
    f32x4 acc[2][4] = {}; f32x4 acc2[2][4] = {};
    for (int k0=0;k0<128;k0+=32){
        #pragma unroll
        for (int p=0;p<2;p++){
            int o = p*64 + so2;
            *reinterpret_cast<half8*>(&Ash[o][sseg*8]) =
                *reinterpret_cast<const half8*>(&f1h[(size_t)o*128 + k0 + sseg*8]);
            *reinterpret_cast<half8*>(&Asl[o][sseg*8]) =
                *reinterpret_cast<const half8*>(&f1l[(size_t)o*128 + k0 + sseg*8]);
        }
        __syncthreads();
        half8 ah[2],al[2],bh[4],bl[4];
        #pragma unroll
        for (int i=0;i<2;i++){
            ah[i] = *reinterpret_cast<const half8*>(&Ash[j0+i*16+l15][l4*8]);
            al[i] = *reinterpret_cast<const half8*>(&Asl[j0+i*16+l15][l4*8]);
        }
        #pragma unroll
        for (int j=0;j<4;j++){
            bh[j] = *reinterpret_cast<const half8*>(&Bch[j*16+l15][k0+l4*8]);
            bl[j] = *reinterpret_cast<const half8*>(&Bcl[j*16+l15][k0+l4*8]);
        }
        #pragma unroll
        for (int i=0;i<2;i++)
            #pragma unroll
            for (int j=0;j<4;j++){
                acc[i][j]  = __builtin_amdgcn_mfma_f32_16x16x32_f16(ah[i], bh[j], acc[i][j], 0,0,0);
                acc2[i][j] = __builtin_amdgcn_mfma_f32_16x16x32_f16(ah[i], bl[j], acc2[i][j],0,0,0);
                acc2[i][j] = __builtin_amdgcn_mfma_f32_16x16x32_f16(al[i], bh[j], acc2[i][j],0,0,0);
            }
        __syncthreads();
    }
    float part[4];
    #pragma unroll
    for (int j=0;j<4;j++) part[j] = 0.f;
    #pragma unroll
    for (int i=0;i<2;i++){
        #pragma unroll
        for (int r=0;r<4;r++){
            int jj = j0 + i*16 + l4*4 + r;
            float b1 = fc1b[jj];
            float w2 = fc2W[jj];
            #pragma unroll
            for (int j=0;j<4;j++){
                float v = acc[i][j][r] + acc2[i][j][r]*LO_INV + b1;
                part[j] = fmaf(w2, gelu_f(v), part[j]);
            }
        }
    }
    #pragma unroll
    for (int j=0;j<4;j++) red[w*4+l4][j*16+l15] = part[j];
    __syncthreads();
    if (tid < 64){
        float s = fc2b[0];
        #pragma unroll
        for (int r=0;r<16;r++) s += red[r][tid];
        out[((size_t)b<<12) + n0 + tid] = s;
    }
}

extern "C" void kernel_launch(void* const* d_in, const int* in_sizes, int n_in,
                              void* d_out, int out_size, void* d_ws, size_t ws_size,
                              hipStream_t stream) {
    const float* x     = (const float*)d_in[0];
    const float* fc0W  = (const float*)d_in[1];
    const float* fc0b  = (const float*)d_in[2];
    const float* gateW = (const float*)d_in[3];
    const float* gateB = (const float*)d_in[4];
    const float* wAre  = (const float*)d_in[5];
    const float* wAim  = (const float*)d_in[6];
    const float* wBre  = (const float*)d_in[7];
    const float* wBim  = (const float*)d_in[8];
    const float* convW = (const float*)d_in[9];
    const float* convB = (const float*)d_in[10];
    const float* fc1W  = (const float*)d_in[11];
    const float* fc1b  = (const float*)d_in[12];
    const float* fc2W  = (const float*)d_in[13];
    const float* fc2b  = (const float*)d_in[14];
    float* out = (float*)d_out;
    char*  wsb = (char*)d_ws;

    float* Fp   = (float*)(wsb + BY_F);
    float* wsum = (float*)(wsb + BY_wsum);
    float* Wcre = (float*)(wsb + BY_Wcre);
    float* Wcim = (float*)(wsb + BY_Wcim);
    float* wl   = (float*)(wsb + BY_wl);
    float* wr   = (float*)(wsb + BY_wr);
    int*   li   = (int*)(wsb + BY_li);
    float* magp = (float*)(wsb + BY_magp);
    float* gate = (float*)(wsb + BY_gate);
    _Float16* hh   = (_Float16*)(wsb + BY_hh);
    _Float16* hl   = (_Float16*)(wsb + BY_hl);
    _Float16* Tffh = (_Float16*)(wsb + BY_Tfh);
    _Float16* Tffl = (_Float16*)(wsb + BY_Tfl);
    _Float16* Tifh = (_Float16*)(wsb + BY_Tih);
    _Float16* Tifl = (_Float16*)(wsb + BY_Til);
    _Float16* Xh   = (_Float16*)(wsb + BY_Xh);
    _Float16* Xl   = (_Float16*)(wsb + BY_Xl);
    _Float16* cWh  = (_Float16*)(wsb + BY_cWh);
    _Float16* cWl  = (_Float16*)(wsb + BY_cWl);
    _Float16* f1h  = (_Float16*)(wsb + BY_f1h);
    _Float16* f1l  = (_Float16*)(wsb + BY_f1l);

    k_tables<<<4096, 256, 0, stream>>>(Tffh, Tffl, Tifh, Tifl);
    k_cft_tables<<<160, 128, 0, stream>>>(Wcre, Wcim, wl, wr, li);
    k_wsum<<<dim3(16384,4), 256, 0, stream>>>(wAre, wAim, wBre, wBim, wsum);
    k_wsplit<<<320, 256, 0, stream>>>(convW, fc1W, cWh, cWl, f1h, f1l);
    k_h0<<<16384, 256, 0, stream>>>(x, fc0W, fc0b, hh, hl);

    for (int layer=0; layer<4; layer++){
        k_cft<<<dim3(64,16), 128, 0, stream>>>(hh, hl, Wcre, Wcim, wl, wr, li, magp);
        k_gate<<<64, 128, 0, stream>>>(magp, gateW, gateB, gate, layer);
        k_fdft<<<512, 256, 0, stream>>>(hh, hl, Tffh, Tffl, Fp);
        k_modemix<<<dim3(64,16), 256, 0, stream>>>(Fp, wsum, gate, Xh, Xl, layer);
        k_flayer<<<dim3(64,64), 256, 0, stream>>>(Xh, Xl, Tifh, Tifl, cWh, cWl, convB,
                                                  hh, hl, layer, layer<3 ? 1:0);
    }
    k_head<<<dim3(64,64), 256, 0, stream>>>(hh, hl, f1h, f1l, fc1b, fc2W, fc2b, out);
    (void)in_sizes; (void)n_in; (void)out_size; (void)ws_size;
}

// Round 16
// 1239.295 us; speedup vs baseline: 1.1706x; 1.0800x over previous
//
#include <hip/hip_runtime.h>
#include <math.h>

#define B_SZ 64
#define WID 128
#define NPT 4096
#define MODES 128
#define LSEG 20
#define MCH 8
#define LM 160   // LSEG*MCH

typedef _Float16 half8 __attribute__((ext_vector_type(8)));
typedef float f32x4 __attribute__((ext_vector_type(4)));
typedef float float2v __attribute__((ext_vector_type(2)));

#define LO_SCALE 2048.0f
#define LO_INV   (1.0f/2048.0f)

// ---------------- workspace layout (bytes), total ~189 MB ----------------
static constexpr size_t BY_F    = 0;                       // fp32 [2 ksplit][8192][256]
static constexpr size_t BY_P    = BY_F + 16777216;         // fp32 [8192][512]
static constexpr size_t BY_wsum = BY_P + 16777216;         // fp32 [4][4][128][128]
static constexpr size_t BY_Wcre = BY_wsum + 1048576;       // fp32 [160][128]
static constexpr size_t BY_Wcim = BY_Wcre + 81920;
static constexpr size_t BY_wl   = BY_Wcim + 81920;         // fp32 [160] (pad)
static constexpr size_t BY_wr   = BY_wl + 1024;
static constexpr size_t BY_li   = BY_wr + 1024;            // int [160]
static constexpr size_t BY_magp = BY_li + 1024;            // fp32 [64][16][128]
static constexpr size_t BY_gate = BY_magp + 524288;        // fp32 [64][128]
static constexpr size_t BY_hh   = BY_gate + 32768;         // f16 [64][128][4096] split-hi
static constexpr size_t BY_hl   = BY_hh + 67108864;        // f16 split-lo
static constexpr size_t BY_Tfh  = BY_hl + 67108864;        // f16 frag-packed fwd [16][128][64][8]
static constexpr size_t BY_Tfl  = BY_Tfh + 2097152;
static constexpr size_t BY_Tih  = BY_Tfl + 2097152;        // f16 frag-packed inv [256][8][64][8]
static constexpr size_t BY_Til  = BY_Tih + 2097152;
static constexpr size_t BY_Xh   = BY_Til + 2097152;        // f16 [64][128][256]
static constexpr size_t BY_Xl   = BY_Xh + 4194304;
static constexpr size_t BY_cWh  = BY_Xl + 4194304;         // f16 [4][128][128]
static constexpr size_t BY_cWl  = BY_cWh + 131072;
static constexpr size_t BY_f1h  = BY_cWl + 131072;         // f16 [128][128]
static constexpr size_t BY_f1l  = BY_f1h + 32768;
static constexpr size_t BY_Bph  = BY_f1l + 32768;          // f16 frag-packed [4][32nt][8ck][64][8]
static constexpr size_t BY_Bpl  = BY_Bph + 1048576;
static constexpr size_t BY_ct   = BY_Bpl + 1048576;        // fp32 [4096]
static constexpr size_t BY_st   = BY_ct + 16384;
static constexpr size_t BY_end  = BY_st + 16384;

__device__ __forceinline__ float gelu_f(float x){
    return 0.5f*x*(1.0f+erff(x*0.70710678118654752f));
}
__device__ __forceinline__ void split_f16(float v, _Float16& hi, _Float16& lo){
    hi = (_Float16)v;
    lo = (_Float16)((v - (float)hi)*LO_SCALE);
}

// ---------------- trig table (4096 distinct angles) ----------------
__global__ void k_trig(float* __restrict__ ct, float* __restrict__ st){
    int m = blockIdx.x*256 + threadIdx.x;   // 4096
    double th = (double)m * (3.14159265358979323846/2048.0);
    double s, c; sincos(th, &s, &c);
    ct[m] = (float)c; st[m] = (float)s;
}

// ---------------- tables (split f16, MFMA-fragment-packed), table-driven ----------------
__global__ void k_tables(const float* __restrict__ ct, const float* __restrict__ st,
                         _Float16* __restrict__ Tffh, _Float16* __restrict__ Tffl,
                         _Float16* __restrict__ Tifh, _Float16* __restrict__ Tifl){
    int idx = blockIdx.x*256 + threadIdx.x;   // 4096*256
    int n = idx >> 8, k2 = idx & 255;
    int f = k2 >> 1;
    int m = (n*f) & 4095;
    float cv = ct[m], sv = st[m];
    float vf = (k2&1) ? -sv : cv;
    {
        _Float16 h1,l1; split_f16(vf, h1, l1);
        int ctile = k2>>4, ck = n>>5;
        int lane = (((n>>3)&3)<<4) | (k2&15);
        int j = n & 7;
        size_t off = (((size_t)(ctile*128 + ck))<<9) + lane*8 + j;
        Tffh[off] = h1; Tffl[off] = l1;
    }
    float vi;
    if (k2 == 0)      vi = 1.0f;
    else if (k2 == 1) vi = 0.0f;
    else              vi = vf;
    {
        _Float16 h2,l2; split_f16(vi, h2, l2);
        int nt = n>>4, ck2 = k2>>5;
        int lane = (((k2>>3)&3)<<4) | (n&15);
        int j = k2 & 7;
        size_t off = (((size_t)(nt*8 + ck2))<<9) + lane*8 + j;
        Tifh[off] = h2; Tifl[off] = l2;
    }
}

__global__ void k_cft_tables(float* __restrict__ Wre, float* __restrict__ Wim,
                             float* __restrict__ wl, float* __restrict__ wr,
                             int* __restrict__ li){
    int idx = blockIdx.x*128 + threadIdx.x;   // 160*128
    if (idx >= LM*MODES) return;
    int lm = idx >> 7;  int f = idx & 127;
    int l = lm / MCH, m = lm % MCH;
    const double PI = 3.14159265358979323846;
    double nodes[8], Tm[8];
    #pragma unroll
    for (int j=0;j<8;j++){
        nodes[j] = -cos((2.0*j+1.0)*PI/16.0);
        Tm[j] = cos((double)m * acos(nodes[j]));
    }
    double wp = (double)f * PI * 0.05;
    double cwre=0.0, cwim=0.0;
    #pragma unroll
    for (int j=0;j<8;j++){
        double sj, cj; sincos(nodes[j]*wp, &sj, &cj);
        cwre += Tm[j]*cj;
        cwim -= Tm[j]*sj;
    }
    cwre *= 0.025; cwim *= 0.025;
    int r = (f*l) % 20;
    double sa = 2.0*PI*(double)r/20.0;
    double shre = cos(sa), shim = -sin(sa);
    Wre[lm*128+f] = (float)(shre*cwre - shim*cwim);
    Wim[lm*128+f] = (float)(shre*cwim + shim*cwre);
    if (f == 0){
        double v = (double)l/20.0 + 0.025*(nodes[m]+1.0);
        int rr = (int)ceil(v*4095.0);
        if (rr > 4095) rr = 4095;
        if (rr < 1) rr = 1;
        int le = rr-1;
        double tl = (double)le/4095.0, tr = (double)rr/4095.0;
        double wrv = (v - tl)/(tr - tl);
        li[lm] = le;
        wl[lm] = (float)(1.0 - wrv);
        wr[lm] = (float)wrv;
    }
}

// sum wA/wB over mode axis
__global__ void k_wsum(const float* __restrict__ wAre, const float* __restrict__ wAim,
                       const float* __restrict__ wBre, const float* __restrict__ wBim,
                       float* __restrict__ out){
    int row  = blockIdx.x*4 + (threadIdx.x>>6);
    int lane = threadIdx.x & 63;
    const float* src = (blockIdx.y==0)?wAre:(blockIdx.y==1)?wAim:(blockIdx.y==2)?wBre:wBim;
    float v = src[(size_t)row*128 + lane] + src[(size_t)row*128 + 64 + lane];
    #pragma unroll
    for (int o=32;o>0;o>>=1) v += __shfl_down(v, o);
    if (lane==0) out[(size_t)blockIdx.y*65536 + row] = v;
}

// build fragment-packed complex-expanded weights B' [4 layers][256 k'][512 n]
__global__ void k_bprime(const float* __restrict__ wsum,
                         _Float16* __restrict__ Bph, _Float16* __restrict__ Bpl){
    int idx = blockIdx.x*256 + threadIdx.x;      // 4*131072
    int layer = idx >> 17;
    int e = idx & 131071;
    int kp = e >> 9, n = e & 511;
    int i = kp >> 1, c = kp & 1;
    int quad = n >> 7, o = n & 127;
    size_t base = (size_t)layer*16384 + (size_t)i*128 + o;
    float v;
    if (quad==0)      v = c ? -wsum[65536 + base]   : wsum[base];
    else if (quad==1) v = c ?  wsum[base]           : wsum[65536 + base];
    else if (quad==2) v = c ? -wsum[3*65536 + base] : wsum[2*65536 + base];
    else              v = c ?  wsum[2*65536 + base] : wsum[3*65536 + base];
    _Float16 hi,lo; split_f16(v,hi,lo);
    int ck = kp >> 5, kloc = kp & 31, nt = n >> 4;
    size_t off = (size_t)layer*131072 + (((size_t)(nt*8 + ck))<<9)
               + (size_t)((((kloc>>3)&3)<<4) | (n&15))*8 + (kloc&7);
    Bph[off]=hi; Bpl[off]=lo;
}

// pre-split conv & fc1 weights (linear layouts)
__global__ void k_wsplit(const float* __restrict__ convW, const float* __restrict__ fc1W,
                         _Float16* __restrict__ cWh, _Float16* __restrict__ cWl,
                         _Float16* __restrict__ f1h, _Float16* __restrict__ f1l){
    int idx = blockIdx.x*256 + threadIdx.x;   // 81920
    if (idx < 65536){
        _Float16 hi,lo; split_f16(convW[idx], hi, lo);
        cWh[idx]=hi; cWl[idx]=lo;
    } else {
        int j = idx - 65536;
        _Float16 hi,lo; split_f16(fc1W[j], hi, lo);
        f1h[j]=hi; f1l[j]=lo;
    }
}

// ---------------- lift: write split h ----------------
__global__ void k_h0(const float* __restrict__ x, const float* __restrict__ w0,
                     const float* __restrict__ b0,
                     _Float16* __restrict__ hh, _Float16* __restrict__ hl){
    int idx = blockIdx.x*256 + threadIdx.x;  // 64*128*512
    int n8 = idx & 511;
    int w  = (idx >> 9) & 127;
    int b  = idx >> 16;
    int n0 = n8*8;
    float w00 = w0[w*2], w01 = w0[w*2+1], bb = b0[w];
    const float* xr = &x[((size_t)b<<12) + n0];
    float4 x0 = *reinterpret_cast<const float4*>(xr);
    float4 x1 = *reinterpret_cast<const float4*>(xr+4);
    float xv[8]={x0.x,x0.y,x0.z,x0.w,x1.x,x1.y,x1.z,x1.w};
    half8 vh, vl;
    #pragma unroll
    for (int q=0;q<8;q++){
        float g = (float)(n0+q) * (1.0f/4095.0f);
        float v = xv[q]*w00 + g*w01 + bb;
        _Float16 hi,lo; split_f16(v,hi,lo);
        vh[q]=hi; vl[q]=lo;
    }
    size_t o = ((size_t)(b*128+w))*4096 + n0;
    *reinterpret_cast<half8*>(&hh[o]) = vh;
    *reinterpret_cast<half8*>(&hl[o]) = vl;
}

// ---------------- CFT magnitude (16 groups of 8 channels) ----------------
__global__ void k_cft(const _Float16* __restrict__ hh, const _Float16* __restrict__ hl,
                      const float* __restrict__ Wre, const float* __restrict__ Wim,
                      const float* __restrict__ wl, const float* __restrict__ wr,
                      const int* __restrict__ li, float* __restrict__ magp){
    int b = blockIdx.x, cg = blockIdx.y;
    int f = threadIdx.x;   // 128
    __shared__ float sig[LM];
    __shared__ float swl[LM], swr[LM];
    __shared__ int   sli[LM];
    for (int s=f; s<LM; s+=128){ swl[s]=wl[s]; swr[s]=wr[s]; sli[s]=li[s]; }
    __syncthreads();
    float acc = 0.f;
    for (int cc=0; cc<8; cc++){
        int c = cg*8 + cc;
        const _Float16* rh = hh + ((size_t)(b*128+c))*4096;
        const _Float16* rl = hl + ((size_t)(b*128+c))*4096;
        for (int s=f; s<LM; s+=128){
            int le = sli[s];
            float v0 = (float)rh[le]   + (float)rl[le]*LO_INV;
            float v1 = (float)rh[le+1] + (float)rl[le+1]*LO_INV;
            sig[s] = swl[s]*v0 + swr[s]*v1;
        }
        __syncthreads();
        float re=0.f, im=0.f;
        #pragma unroll 8
        for (int s=0;s<LM;s++){
            float sv = sig[s];
            re = fmaf(sv, Wre[s*128+f], re);
            im = fmaf(sv, Wim[s*128+f], im);
        }
        acc += sqrtf(re*re+im*im);
        __syncthreads();
    }
    magp[(b*16+cg)*128 + f] = acc;
}

__global__ void k_gate(const float* __restrict__ magp, const float* __restrict__ gW,
                       const float* __restrict__ gB, float* __restrict__ gate, int layer){
    int b = blockIdx.x, w = threadIdx.x;
    __shared__ float ms[128];
    float s = 0.f;
    #pragma unroll
    for (int g=0; g<16; g++) s += magp[(b*16+g)*128 + w];
    ms[w] = s * (1.0f/128.0f);
    __syncthreads();
    const float* gwr = gW + ((size_t)layer*128 + w)*128;
    float a = gB[layer*128 + w];
    #pragma unroll 8
    for (int fq=0; fq<128; fq++) a = fmaf(ms[fq], gwr[fq], a);
    gate[b*128+w] = 1.0f/(1.0f+expf(-a));
}

// ---------------- forward DFT: 64x128 block, split-K=2, A-LDS dbuf, B direct fragments ----------------
__global__ __launch_bounds__(256) void k_fdft(
        const _Float16* __restrict__ hh, const _Float16* __restrict__ hl,
        const _Float16* __restrict__ Tffh, const _Float16* __restrict__ Tffl,
        float* __restrict__ Fp){
    __shared__ _Float16 Ah[2][64][40], Al[2][64][40];
    int id = blockIdx.x;
    int swz = (id & 7)*64 + (id >> 3);        // bijective for 512
    int rg = swz & 127, cg = (swz >> 7) & 1, ks = swz >> 8;
    int row0 = rg*64, col0 = cg*128, kbase = ks*2048;
    int tid = threadIdx.x, lane = tid & 63, w = tid >> 6;
    int wr = (w>>1)*32, wc = (w&1)*64;
    int l15 = lane & 15, l4 = lane >> 4;
    f32x4 acc[2][4] = {}; f32x4 acc2[2][4] = {};
    int srow = tid >> 2, sseg = tid & 3;
    const _Float16* pa_h = hh + (size_t)(row0+srow)*4096 + kbase + sseg*8;
    const _Float16* pa_l = hl + (size_t)(row0+srow)*4096 + kbase + sseg*8;
    int ct0 = (col0 + wc) >> 4;
    int ckb = ks*64;
    const _Float16* pfh = Tffh + (size_t)lane*8;
    const _Float16* pfl = Tffl + (size_t)lane*8;
    half8 a0h,a0l,a1h,a1l;
    half8 bf0[8], bf1[8];
#define LOADA(xh,xl,ck) do{ \
    xh = *reinterpret_cast<const half8*>(pa_h + (size_t)(ck)*32); \
    xl = *reinterpret_cast<const half8*>(pa_l + (size_t)(ck)*32); }while(0)
#define WRITEA(xh,xl,buf) do{ \
    *reinterpret_cast<half8*>(&Ah[buf][srow][sseg*8]) = xh; \
    *reinterpret_cast<half8*>(&Al[buf][srow][sseg*8]) = xl; }while(0)
#define LOADB(dst,ck) do{ \
    _Pragma("unroll") for (int j=0;j<4;j++){ \
        dst[j]   = *reinterpret_cast<const half8*>(pfh + (((size_t)(ct0+j)*128 + ckb + (ck))<<9)); \
        dst[4+j] = *reinterpret_cast<const half8*>(pfl + (((size_t)(ct0+j)*128 + ckb + (ck))<<9)); } }while(0)
#define MMF(buf,BF) do{ \
    _Pragma("unroll") for (int i=0;i<2;i++){ \
        half8 fah = *reinterpret_cast<const half8*>(&Ah[buf][wr + i*16 + l15][l4*8]); \
        half8 fal = *reinterpret_cast<const half8*>(&Al[buf][wr + i*16 + l15][l4*8]); \
        _Pragma("unroll") for (int j=0;j<4;j++){ \
            acc[i][j]  = __builtin_amdgcn_mfma_f32_16x16x32_f16(fah, BF[j],   acc[i][j], 0,0,0); \
            acc2[i][j] = __builtin_amdgcn_mfma_f32_16x16x32_f16(fah, BF[4+j], acc2[i][j],0,0,0); \
            acc2[i][j] = __builtin_amdgcn_mfma_f32_16x16x32_f16(fal, BF[j],   acc2[i][j],0,0,0); } } }while(0)
    LOADA(a0h,a0l,0); WRITEA(a0h,a0l,0);
    LOADA(a0h,a0l,1);
    LOADA(a1h,a1l,2);
    LOADB(bf0,0); LOADB(bf1,1);
    __syncthreads();
    for (int tt=0; tt<32; ++tt){
        int t = tt*2;
        MMF(0,bf0);
        WRITEA(a0h,a0l,1);
        if (t+2 < 64) LOADB(bf0, t+2);
        if (t+3 < 64) LOADA(a0h,a0l, t+3);
        __syncthreads();
        MMF(1,bf1);
        if (t+2 < 64) WRITEA(a1h,a1l,0);
        if (t+3 < 64) LOADB(bf1, t+3);
        if (t+4 < 64) LOADA(a1h,a1l, t+4);
        __syncthreads();
    }
#undef LOADA
#undef WRITEA
#undef LOADB
#undef MMF
    float* Fo = Fp + (size_t)ks*2097152;
    #pragma unroll
    for (int i=0;i<2;i++)
        #pragma unroll
        for (int j=0;j<4;j++)
            #pragma unroll
            for (int r=0;r<4;r++){
                int row = row0 + wr + i*16 + l4*4 + r;
                int col = col0 + wc + j*16 + l15;
                Fo[(size_t)row*256 + col] = acc[i][j][r] + acc2[i][j][r]*LO_INV;
            }
}

// ---------------- P = [Fre|Fim] x B' : M=8192, K=256, N=512 MFMA GEMM ----------------
// A staged in LDS (sums 2 split-K F parts, splits f16 on the fly); B direct packed fragments.
__global__ __launch_bounds__(256) void k_pmix(
        const float* __restrict__ Fp,
        const _Float16* __restrict__ Bph, const _Float16* __restrict__ Bpl,
        float* __restrict__ P, int layer){
    __shared__ _Float16 Ash[64][40], Asl[64][40];
    int mt = blockIdx.x;          // 128 m-tiles of 64
    int nb = blockIdx.y;          // 4 col-blocks of 128
    int b  = mt >> 1;
    int f0 = (mt & 1) * 64;
    int tid = threadIdx.x, lane = tid & 63, w = tid >> 6;
    int wr = (w>>1)*32, wn = (w&1)*64;
    int l15 = lane & 15, l4 = lane >> 4;
    int sf = tid & 63, sig = tid >> 6;
    f32x4 acc[2][4] = {}; f32x4 acc2[2][4] = {};
    int nt0 = (nb*128 + wn) >> 4;
    const _Float16* pBh = Bph + (size_t)layer*131072 + (size_t)lane*8;
    const _Float16* pBl = Bpl + (size_t)layer*131072 + (size_t)lane*8;
    for (int ck=0; ck<8; ++ck){
        #pragma unroll
        for (int q=0;q<4;q++){
            int i = ck*16 + sig*4 + q;
            size_t idx = ((size_t)(b*128 + i))*256 + 2*(f0+sf);
            float2v v0 = *reinterpret_cast<const float2v*>(&Fp[idx]);
            float2v v1 = *reinterpret_cast<const float2v*>(&Fp[idx + 2097152]);
            float re = v0.x + v1.x, im = v0.y + v1.y;
            int kloc = 2*(sig*4+q);
            _Float16 h0,l0,h1,l1;
            split_f16(re,h0,l0); split_f16(im,h1,l1);
            Ash[sf][kloc] = h0; Ash[sf][kloc+1] = h1;
            Asl[sf][kloc] = l0; Asl[sf][kloc+1] = l1;
        }
        __syncthreads();
        half8 bh[4], bl[4];
        #pragma unroll
        for (int j=0;j<4;j++){
            size_t off = ((size_t)((nt0+j)*8 + ck)) << 9;
            bh[j] = *reinterpret_cast<const half8*>(pBh + off);
            bl[j] = *reinterpret_cast<const half8*>(pBl + off);
        }
        #pragma unroll
        for (int i=0;i<2;i++){
            half8 ah = *reinterpret_cast<const half8*>(&Ash[wr+i*16+l15][l4*8]);
            half8 al = *reinterpret_cast<const half8*>(&Asl[wr+i*16+l15][l4*8]);
            #pragma unroll
            for (int j=0;j<4;j++){
                acc[i][j]  = __builtin_amdgcn_mfma_f32_16x16x32_f16(ah, bh[j], acc[i][j], 0,0,0);
                acc2[i][j] = __builtin_amdgcn_mfma_f32_16x16x32_f16(ah, bl[j], acc2[i][j],0,0,0);
                acc2[i][j] = __builtin_amdgcn_mfma_f32_16x16x32_f16(al, bh[j], acc2[i][j],0,0,0);
            }
        }
        __syncthreads();
    }
    int m0 = mt*64;
    #pragma unroll
    for (int i=0;i<2;i++)
        #pragma unroll
        for (int j=0;j<4;j++)
            #pragma unroll
            for (int r=0;r<4;r++){
                int row = wr + i*16 + l4*4 + r;
                int col = wn + j*16 + l15;
                P[(size_t)(m0+row)*512 + nb*128 + col] = acc[i][j][r] + acc2[i][j][r]*LO_INV;
            }
}

// ---------------- gate mix + scale + split + transpose to X[b][o][k2] ----------------
__global__ __launch_bounds__(256) void k_gmix(
        const float* __restrict__ P, const float* __restrict__ gate,
        _Float16* __restrict__ Xh, _Float16* __restrict__ Xl){
    __shared__ float S[128][16][4];
    int b = blockIdx.x, og = blockIdx.y;   // 64 x 8
    int tid = threadIdx.x;
    {
        int f = tid >> 1, seg = tid & 1;
        #pragma unroll
        for (int qq=0; qq<2; ++qq){
            int quad = seg*2 + qq;
            const float* src = &P[((size_t)(b*128+f))*512 + quad*128 + og*16];
            #pragma unroll
            for (int jj=0; jj<4; ++jj){
                float4 v = *reinterpret_cast<const float4*>(src + jj*4);
                S[f][jj*4+0][quad] = v.x;
                S[f][jj*4+1][quad] = v.y;
                S[f][jj*4+2][quad] = v.z;
                S[f][jj*4+3][quad] = v.w;
            }
        }
    }
    __syncthreads();
    int oo = tid & 15, fg = tid >> 4;
    int o = og*16 + oo;
    float g = gate[b*128 + o];
    half8 xh0, xh1, xl0, xl1;
    #pragma unroll
    for (int ff=0; ff<8; ++ff){
        int f = fg*8 + ff;
        float pre = g*S[f][oo][0] + (1.f-g)*S[f][oo][2];
        float pim = g*S[f][oo][1] + (1.f-g)*S[f][oo][3];
        float s = (f==0) ? (1.0f/4096.0f) : (2.0f/4096.0f);
        pre *= s; pim *= s;
        if (f==0) pim = 0.f;
        _Float16 h0,l0,h1,l1;
        split_f16(pre,h0,l0); split_f16(pim,h1,l1);
        if (ff<4){ xh0[2*ff]=h0; xh0[2*ff+1]=h1; xl0[2*ff]=l0; xl0[2*ff+1]=l1; }
        else { xh1[2*(ff-4)]=h0; xh1[2*(ff-4)+1]=h1; xl1[2*(ff-4)]=l0; xl1[2*(ff-4)+1]=l1; }
    }
    size_t base = ((size_t)(b*128+o))*256 + fg*16;
    *reinterpret_cast<half8*>(&Xh[base])   = xh0;
    *reinterpret_cast<half8*>(&Xh[base+8]) = xh1;
    *reinterpret_cast<half8*>(&Xl[base])   = xl0;
    *reinterpret_cast<half8*>(&Xl[base+8]) = xl1;
}

// ---------------- fused in-place layer (R11 proven): 12-chunk pipeline; Ti via packed fragments ----------------
__global__ __launch_bounds__(256) void k_flayer(
    const _Float16* __restrict__ Xh, const _Float16* __restrict__ Xl,
    const _Float16* __restrict__ Tifh, const _Float16* __restrict__ Tifl,
    const _Float16* __restrict__ cWh, const _Float16* __restrict__ cWl,
    const float* __restrict__ convB,
    _Float16* __restrict__ hh, _Float16* __restrict__ hl,
    int layer, int applyGelu){
    __shared__ _Float16 As_h[2][128][40], As_l[2][128][40];
    __shared__ _Float16 Bs_h[2][64][40],  Bs_l[2][64][40];
    int n0 = blockIdx.x*64;
    int b  = blockIdx.y;
    int tid = threadIdx.x, lane = tid & 63, w = tid >> 6;
    int l15 = lane & 15, l4 = lane >> 4;
    int o0 = w*32;
    int aro = tid >> 2, asl = tid & 3;
    int ctc = tid >> 3, ctn = tid & 7;
    int ocp = ((tid >> 6) ^ (tid & 3));
    const _Float16* cA_h = cWh + (size_t)layer*16384 + (size_t)aro*128 + asl*8;
    const _Float16* cA_l = cWl + (size_t)layer*16384 + (size_t)aro*128 + asl*8;
    const _Float16* xA_h = Xh + ((size_t)(b*128 + aro))*256 + asl*8;
    const _Float16* xA_l = Xl + ((size_t)(b*128 + aro))*256 + asl*8;
    const _Float16* hB_h = hh + ((size_t)(b*128 + ctc))*4096 + n0 + ctn*8;
    const _Float16* hB_l = hl + ((size_t)(b*128 + ctc))*4096 + n0 + ctn*8;
    int nt0 = n0 >> 4;
    const _Float16* pTh = Tifh + (size_t)lane*8;
    const _Float16* pTl = Tifl + (size_t)lane*8;
    f32x4 acc[2][4] = {}; f32x4 acc2[2][4] = {};
    half8 rA[6], rB[6];
    half8 bf0[8], bf1[8];
#define LOADR(r,ck) do{ \
    if ((ck) < 4){ size_t kk = (size_t)(ck)*32; \
        r[0] = *reinterpret_cast<const half8*>(cA_h + kk); \
        r[1] = *reinterpret_cast<const half8*>(cA_l + kk); \
        r[2] = *reinterpret_cast<const half8*>(cA_h + 64*128 + kk); \
        r[3] = *reinterpret_cast<const half8*>(cA_l + 64*128 + kk); \
        r[4] = *reinterpret_cast<const half8*>(hB_h + (size_t)(ck)*32*4096); \
        r[5] = *reinterpret_cast<const half8*>(hB_l + (size_t)(ck)*32*4096); \
    } else { size_t kk = (size_t)((ck)-4)*32; \
        r[0] = *reinterpret_cast<const half8*>(xA_h + kk); \
        r[1] = *reinterpret_cast<const half8*>(xA_l + kk); \
        r[2] = *reinterpret_cast<const half8*>(xA_h + 64*256 + kk); \
        r[3] = *reinterpret_cast<const half8*>(xA_l + 64*256 + kk); } }while(0)
#define WRITER(r,buf,ck) do{ \
    *reinterpret_cast<half8*>(&As_h[buf][aro][asl*8])    = r[0]; \
    *reinterpret_cast<half8*>(&As_l[buf][aro][asl*8])    = r[1]; \
    *reinterpret_cast<half8*>(&As_h[buf][aro+64][asl*8]) = r[2]; \
    *reinterpret_cast<half8*>(&As_l[buf][aro+64][asl*8]) = r[3]; \
    if ((ck) < 4){ \
        _Pragma("unroll") for (int j2=0;j2<8;j2++){ \
            int n1 = ctn*8 + j2; \
            Bs_h[buf][n1][ocp*8 + (ctc&7)] = r[4][j2]; \
            Bs_l[buf][n1][ocp*8 + (ctc&7)] = r[5][j2]; } } }while(0)
#define LOADBF(dst,ckp) do{ \
    _Pragma("unroll") for (int j=0;j<4;j++){ \
        dst[j]   = *reinterpret_cast<const half8*>(pTh + (((size_t)((nt0+j)*8 + (ckp)))<<9)); \
        dst[4+j] = *reinterpret_cast<const half8*>(pTl + (((size_t)((nt0+j)*8 + (ckp)))<<9)); } }while(0)
#define MML(buf,ck,BF) do{ \
    half8 bh[4], bl[4]; \
    if ((ck) < 4){ \
        _Pragma("unroll") for (int j=0;j<4;j++){ \
            int n = j*16 + l15; int sl = (l4 ^ ((n>>3)&3)); \
            bh[j] = *reinterpret_cast<const half8*>(&Bs_h[buf][n][sl*8]); \
            bl[j] = *reinterpret_cast<const half8*>(&Bs_l[buf][n][sl*8]); } \
    } else { \
        _Pragma("unroll") for (int j=0;j<4;j++){ bh[j] = BF[j]; bl[j] = BF[4+j]; } } \
    _Pragma("unroll") for (int i=0;i<2;i++){ \
        half8 ah = *reinterpret_cast<const half8*>(&As_h[buf][o0+i*16+l15][l4*8]); \
        half8 al = *reinterpret_cast<const half8*>(&As_l[buf][o0+i*16+l15][l4*8]); \
        _Pragma("unroll") for (int j=0;j<4;j++){ \
            acc[i][j]  = __builtin_amdgcn_mfma_f32_16x16x32_f16(ah, bh[j], acc[i][j], 0,0,0); \
            acc2[i][j] = __builtin_amdgcn_mfma_f32_16x16x32_f16(ah, bl[j], acc2[i][j],0,0,0); \
            acc2[i][j] = __builtin_amdgcn_mfma_f32_16x16x32_f16(al, bh[j], acc2[i][j],0,0,0); } } }while(0)
    LOADR(rA, 0);
    WRITER(rA, 0, 0);
    LOADR(rA, 1);
    LOADR(rB, 2);
    __syncthreads();
    #pragma unroll
    for (int tt=0; tt<6; ++tt){
        const int t = 2*tt;
        MML(0, t, bf0);
        WRITER(rA, 1, t+1);
        if (t+2 >= 4 && t+2 < 12) LOADBF(bf0, t+2-4);
        if (t+3 < 12) LOADR(rA, t+3);
        __syncthreads();
        MML(1, t+1, bf1);
        if (t+2 < 12) WRITER(rB, 0, t+2);
        if (t+3 >= 4 && t+3 < 12) LOADBF(bf1, t+3-4);
        if (t+4 < 12) LOADR(rB, t+4);
        __syncthreads();
    }
#undef LOADR
#undef WRITER
#undef LOADBF
#undef MML
    #pragma unroll
    for (int i=0;i<2;i++)
        #pragma unroll
        for (int j=0;j<4;j++)
            #pragma unroll
            for (int r=0;r<4;r++){
                int o = o0 + i*16 + l4*4 + r;
                int n = n0 + j*16 + l15;
                float v = acc[i][j][r] + acc2[i][j][r]*LO_INV + convB[layer*128+o];
                if (applyGelu) v = gelu_f(v);
                _Float16 hi,lo; split_f16(v,hi,lo);
                size_t oi = ((size_t)(b*128+o))*4096 + n;
                hh[oi] = hi; hl[oi] = lo;
            }
}

// ---------------- head (MFMA) ----------------
__global__ __launch_bounds__(256) void k_head(
        const _Float16* __restrict__ hh, const _Float16* __restrict__ hl,
        const _Float16* __restrict__ f1h, const _Float16* __restrict__ f1l,
        const float* __restrict__ fc1b,
        const float* __restrict__ fc2W, const float* __restrict__ fc2b,
        float* __restrict__ out){
    __shared__ _Float16 Bch[64][136], Bcl[64][136];
    __shared__ _Float16 Ash[128][40], Asl[128][40];
    __shared__ float red[16][64];
    int n0 = blockIdx.x*64;
    int b  = blockIdx.y;
    int tid = threadIdx.x, lane = tid & 63, w = tid >> 6;
    int l15 = lane & 15, l4 = lane >> 4;
    int j0 = w*32;
    {
        int c = tid & 127, nh = tid >> 7;
        const _Float16* rh = hh + ((size_t)(b*128+c))*4096 + n0 + nh*32;
        const _Float16* rl = hl + ((size_t)(b*128+c))*4096 + n0 + nh*32;
        #pragma unroll
        for (int j=0;j<4;j++){
            half8 vhv = *reinterpret_cast<const half8*>(rh + j*8);
            half8 vlv = *reinterpret_cast<const half8*>(rl + j*8);
            #pragma unroll
            for (int q=0;q<8;q++){
                int n = nh*32 + j*8 + q;
                Bch[n][c] = vhv[q];
                Bcl[n][c] = vlv[q];
            }
        }
    }
    __syncthreads();
    int so2 = tid >> 2, sseg = tid & 3;
    f32x4 acc[2][4] = {}; f32x4 acc2[2][4] = {};
    for (int k0=0;k0<128;k0+=32){
        #pragma unroll
        for (int p=0;p<2;p++){
            int o = p*64 + so2;
            *reinterpret_cast<half8*>(&Ash[o][sseg*8]) =
                *reinterpret_cast<const half8*>(&f1h[(size_t)o*128 + k0 + sseg*8]);
            *reinterpret_cast<half8*>(&Asl[o][sseg*8]) =
                *reinterpret_cast<const half8*>(&f1l[(size_t)o*128 + k0 + sseg*8]);
        }
        __syncthreads();
        half8 ah[2],al[2],bh[4],bl[4];
        #pragma unroll
        for (int i=0;i<2;i++){
            ah[i] = *reinterpret_cast<const half8*>(&Ash[j0+i*16+l15][l4*8]);
            al[i] = *reinterpret_cast<const half8*>(&Asl[j0+i*16+l15][l4*8]);
        }
        #pragma unroll
        for (int j=0;j<4;j++){
            bh[j] = *reinterpret_cast<const half8*>(&Bch[j*16+l15][k0+l4*8]);
            bl[j] = *reinterpret_cast<const half8*>(&Bcl[j*16+l15][k0+l4*8]);
        }
        #pragma unroll
        for (int i=0;i<2;i++)
            #pragma unroll
            for (int j=0;j<4;j++){
                acc[i][j]  = __builtin_amdgcn_mfma_f32_16x16x32_f16(ah[i], bh[j], acc[i][j], 0,0,0);
                acc2[i][j] = __builtin_amdgcn_mfma_f32_16x16x32_f16(ah[i], bl[j], acc2[i][j],0,0,0);
                acc2[i][j] = __builtin_amdgcn_mfma_f32_16x16x32_f16(al[i], bh[j], acc2[i][j],0,0,0);
            }
        __syncthreads();
    }
    float part[4];
    #pragma unroll
    for (int j=0;j<4;j++) part[j] = 0.f;
    #pragma unroll
    for (int i=0;i<2;i++){
        #pragma unroll
        for (int r=0;r<4;r++){
            int jj = j0 + i*16 + l4*4 + r;
            float b1 = fc1b[jj];
            float w2 = fc2W[jj];
            #pragma unroll
            for (int j=0;j<4;j++){
                float v = acc[i][j][r] + acc2[i][j][r]*LO_INV + b1;
                part[j] = fmaf(w2, gelu_f(v), part[j]);
            }
        }
    }
    #pragma unroll
    for (int j=0;j<4;j++) red[w*4+l4][j*16+l15] = part[j];
    __syncthreads();
    if (tid < 64){
        float s = fc2b[0];
        #pragma unroll
        for (int r=0;r<16;r++) s += red[r][tid];
        out[((size_t)b<<12) + n0 + tid] = s;
    }
}

extern "C" void kernel_launch(void* const* d_in, const int* in_sizes, int n_in,
                              void* d_out, int out_size, void* d_ws, size_t ws_size,
                              hipStream_t stream) {
    const float* x     = (const float*)d_in[0];
    const float* fc0W  = (const float*)d_in[1];
    const float* fc0b  = (const float*)d_in[2];
    const float* gateW = (const float*)d_in[3];
    const float* gateB = (const float*)d_in[4];
    const float* wAre  = (const float*)d_in[5];
    const float* wAim  = (const float*)d_in[6];
    const float* wBre  = (const float*)d_in[7];
    const float* wBim  = (const float*)d_in[8];
    const float* convW = (const float*)d_in[9];
    const float* convB = (const float*)d_in[10];
    const float* fc1W  = (const float*)d_in[11];
    const float* fc1b  = (const float*)d_in[12];
    const float* fc2W  = (const float*)d_in[13];
    const float* fc2b  = (const float*)d_in[14];
    float* out = (float*)d_out;
    char*  wsb = (char*)d_ws;

    float* Fp   = (float*)(wsb + BY_F);
    float* P    = (float*)(wsb + BY_P);
    float* wsum = (float*)(wsb + BY_wsum);
    float* Wcre = (float*)(wsb + BY_Wcre);
    float* Wcim = (float*)(wsb + BY_Wcim);
    float* wl   = (float*)(wsb + BY_wl);
    float* wr   = (float*)(wsb + BY_wr);
    int*   li   = (int*)(wsb + BY_li);
    float* magp = (float*)(wsb + BY_magp);
    float* gate = (float*)(wsb + BY_gate);
    _Float16* hh   = (_Float16*)(wsb + BY_hh);
    _Float16* hl   = (_Float16*)(wsb + BY_hl);
    _Float16* Tffh = (_Float16*)(wsb + BY_Tfh);
    _Float16* Tffl = (_Float16*)(wsb + BY_Tfl);
    _Float16* Tifh = (_Float16*)(wsb + BY_Tih);
    _Float16* Tifl = (_Float16*)(wsb + BY_Til);
    _Float16* Xh   = (_Float16*)(wsb + BY_Xh);
    _Float16* Xl   = (_Float16*)(wsb + BY_Xl);
    _Float16* cWh  = (_Float16*)(wsb + BY_cWh);
    _Float16* cWl  = (_Float16*)(wsb + BY_cWl);
    _Float16* f1h  = (_Float16*)(wsb + BY_f1h);
    _Float16* f1l  = (_Float16*)(wsb + BY_f1l);
    _Float16* Bph  = (_Float16*)(wsb + BY_Bph);
    _Float16* Bpl  = (_Float16*)(wsb + BY_Bpl);
    float* ct   = (float*)(wsb + BY_ct);
    float* st   = (float*)(wsb + BY_st);

    k_trig<<<16, 256, 0, stream>>>(ct, st);
    k_tables<<<4096, 256, 0, stream>>>(ct, st, Tffh, Tffl, Tifh, Tifl);
    k_cft_tables<<<160, 128, 0, stream>>>(Wcre, Wcim, wl, wr, li);
    k_wsum<<<dim3(16384,4), 256, 0, stream>>>(wAre, wAim, wBre, wBim, wsum);
    k_bprime<<<2048, 256, 0, stream>>>(wsum, Bph, Bpl);
    k_wsplit<<<320, 256, 0, stream>>>(convW, fc1W, cWh, cWl, f1h, f1l);
    k_h0<<<16384, 256, 0, stream>>>(x, fc0W, fc0b, hh, hl);

    for (int layer=0; layer<4; layer++){
        k_cft<<<dim3(64,16), 128, 0, stream>>>(hh, hl, Wcre, Wcim, wl, wr, li, magp);
        k_gate<<<64, 128, 0, stream>>>(magp, gateW, gateB, gate, layer);
        k_fdft<<<512, 256, 0, stream>>>(hh, hl, Tffh, Tffl, Fp);
        k_pmix<<<dim3(128,4), 256, 0, stream>>>(Fp, Bph, Bpl, P, layer);
        k_gmix<<<dim3(64,8), 256, 0, stream>>>(P, gate, Xh, Xl);
        k_flayer<<<dim3(64,64), 256, 0, stream>>>(Xh, Xl, Tifh, Tifl, cWh, cWl, convB,
                                                  hh, hl, layer, layer<3 ? 1:0);
    }
    k_head<<<dim3(64,64), 256, 0, stream>>>(hh, hl, f1h, f1l, fc1b, fc2W, fc2b, out);
    (void)in_sizes; (void)n_in; (void)out_size; (void)ws_size;
}